// Round 5
// baseline (188.997 us; speedup 1.0000x reference)
//
#include <hip/hip_runtime.h>
#include <cstdint>

// Problem constants: B=2, L=2048, D=1024, H=16, DK=64
#define SEQ     2048
#define DMODEL  1024
#define NHEAD   16
#define DKH     64
#define NTOK    4096      // B*L
#define LDQKV   3072      // qkv buffer row stride (q|k|v)

typedef __bf16 bf16x8 __attribute__((ext_vector_type(8)));
typedef __bf16 bf16x4 __attribute__((ext_vector_type(4)));
typedef float  f32x4  __attribute__((ext_vector_type(4)));

#define MFMA_BF16(a, b, c) __builtin_amdgcn_mfma_f32_16x16x32_bf16((a), (b), (c), 0, 0, 0)

// 0.125 * log2(e): folded into wq/bq at pack time. Softmax shift dropped
// entirely — exp2(s) scales O and l identically, cancels in O/l.
// (This is also what makes key-range splitting combine-by-ADD: partial O and
// partial l over disjoint key ranges just sum, no max-rescale.)
#define C2F 0.18033688f

// raw v_exp_f32 — libm exp2f is ~7 instrs (range/denorm handling) and was
// the round-6 VALU bottleneck (VALUBusy/MfmaUtil = 3.3).
__device__ inline float fast_exp2(float x) {
#if __has_builtin(__builtin_amdgcn_exp2f)
  return __builtin_amdgcn_exp2f(x);
#else
  return __expf(x * 0.69314718056f);
#endif
}

// async global->LDS copy, 16B per lane; LDS dest is wave-uniform base + lane*16
__device__ inline void async_copy16(const void* g, void* l) {
  __builtin_amdgcn_global_load_lds(
      reinterpret_cast<const __attribute__((address_space(1))) void*>(
          reinterpret_cast<uintptr_t>(g)),
      reinterpret_cast<__attribute__((address_space(3))) void*>(
          reinterpret_cast<uintptr_t>(l)),
      16, 0, 0);
}

__device__ inline bf16x4 cvt4(float4 v) {
  bf16x4 r;
  r[0] = (__bf16)v.x; r[1] = (__bf16)v.y; r[2] = (__bf16)v.z; r[3] = (__bf16)v.w;
  return r;
}

// ---------------- pack: fp32 -> bf16 casts + weight/bias concat ----------------
// wq and bq are pre-scaled by C2F (softmax scale folded into Q).
__global__ __launch_bounds__(256) void pack_kernel(
    const float4* __restrict__ x,
    const float4* __restrict__ wq, const float4* __restrict__ wk,
    const float4* __restrict__ wv, const float4* __restrict__ wo,
    const float4* __restrict__ bq, const float4* __restrict__ bk,
    const float4* __restrict__ bv,
    bf16x4* __restrict__ xb, bf16x4* __restrict__ wqkv,
    bf16x4* __restrict__ wob, float4* __restrict__ bcat)
{
  const int NX = NTOK * DMODEL / 4;       // 1048576 float4 groups of x
  const int NW = DMODEL * DMODEL / 4;     // 262144 per weight
  const int TOT = NX + 4 * NW + 3 * (DMODEL / 4);
  for (int g = blockIdx.x * 256 + threadIdx.x; g < TOT; g += gridDim.x * 256) {
    if (g < NX) {
      xb[g] = cvt4(x[g]);
    } else if (g < NX + 3 * NW) {
      int g2 = g - NX;
      const float4* s = (g2 < NW) ? wq : (g2 < 2 * NW ? wk : wv);
      float4 v = s[g2 & (NW - 1)];
      if (g2 < NW) { v.x *= C2F; v.y *= C2F; v.z *= C2F; v.w *= C2F; }
      wqkv[g2] = cvt4(v);
    } else if (g < NX + 4 * NW) {
      int g3 = g - NX - 3 * NW;
      wob[g3] = cvt4(wo[g3]);
    } else {
      int g4 = g - NX - 4 * NW;
      const float4* s = (g4 < 256) ? bq : (g4 < 512 ? bk : bv);
      float4 v = s[g4 & 255];
      if (g4 < 256) { v.x *= C2F; v.y *= C2F; v.z *= C2F; v.w *= C2F; }
      bcat[g4] = v;
    }
  }
}

// ---------------- GEMM: C[M,N] = A[M,K] * W[N,K]^T + bias, K=1024 -------------
// 128xBN tile (BN=128 or 64), double-buffered LDS staging.
template<int BN>
__global__ __launch_bounds__(256) void gemm_bias(
    const __bf16* __restrict__ A, const __bf16* __restrict__ W,
    const float* __restrict__ bias, void* __restrict__ C,
    int ldc, int out_bf16)
{
  constexpr int K = 1024;
  constexpr int JT = BN / 32;          // j-tiles per wave: 4 or 2
  __shared__ __bf16 sA[2][128 * 32];
  __shared__ __bf16 sB[2][BN * 32];
  const int tid  = threadIdx.x;
  const int wave = tid >> 6, lane = tid & 63;
  const int quad = lane >> 4, l16 = lane & 15;
  const size_t m0 = (size_t)blockIdx.x * 128;
  const size_t n0 = (size_t)blockIdx.y * BN;
  const int wm = (wave & 1) * 64, wn = (wave >> 1) * (BN / 2);

  const int g0 = wave * 2;
  const int sr = lane >> 2;          // row within 16-row group
  const int sc = (lane & 3) * 8;     // bf16 col offset within BK=32
  const __bf16* pa0 = A + (m0 + g0 * 16 + sr) * K + sc;
  const __bf16* pa1 = pa0 + 16 * K;
  const int brow = (BN == 128) ? g0 * 16 : wave * 16;
  const __bf16* pb0 = W + (n0 + brow + sr) * K + sc;
  const int lo  = g0 * 512;
  const int lob = (BN == 128) ? g0 * 512 : wave * 512;

  f32x4 acc[4][JT];
  const f32x4 z = {0.f, 0.f, 0.f, 0.f};
#pragma unroll
  for (int i = 0; i < 4; ++i)
#pragma unroll
    for (int j = 0; j < JT; ++j) acc[i][j] = z;

  // prologue: stage k0=0 into buffer 0
  async_copy16(pa0, &sA[0][lo]);
  async_copy16(pa1, &sA[0][lo + 512]);
  async_copy16(pb0, &sB[0][lob]);
  if (BN == 128) async_copy16(pb0 + 16 * K, &sB[0][lob + 512]);

  for (int k0 = 0; k0 < K; k0 += 32) {
    const int cur = (k0 >> 5) & 1, nxt = cur ^ 1;
    __syncthreads();                 // tile k0 staged; prev reads of nxt done
    if (k0 + 32 < K) {
      async_copy16(pa0 + k0 + 32, &sA[nxt][lo]);
      async_copy16(pa1 + k0 + 32, &sA[nxt][lo + 512]);
      async_copy16(pb0 + k0 + 32, &sB[nxt][lob]);
      if (BN == 128) async_copy16(pb0 + 16 * K + k0 + 32, &sB[nxt][lob + 512]);
    }

    bf16x8 af[4], bw[JT];
#pragma unroll
    for (int i = 0; i < 4; ++i)
      af[i] = *(const bf16x8*)(&sA[cur][(wm + i * 16 + l16) * 32 + quad * 8]);
#pragma unroll
    for (int j = 0; j < JT; ++j)
      bw[j] = *(const bf16x8*)(&sB[cur][(wn + j * 16 + l16) * 32 + quad * 8]);
#pragma unroll
    for (int i = 0; i < 4; ++i)
#pragma unroll
      for (int j = 0; j < JT; ++j)
        acc[i][j] = MFMA_BF16(af[i], bw[j], acc[i][j]);
  }

  float bi[JT];
#pragma unroll
  for (int j = 0; j < JT; ++j) bi[j] = bias[n0 + wn + j * 16 + l16];

#pragma unroll
  for (int i = 0; i < 4; ++i) {
#pragma unroll
    for (int j = 0; j < JT; ++j) {
#pragma unroll
      for (int r = 0; r < 4; ++r) {
        size_t row = m0 + wm + i * 16 + quad * 4 + r;
        size_t col = n0 + wn + j * 16 + l16;
        float v = acc[i][j][r] + bi[j];
        if (out_bf16) ((__bf16*)C)[row * ldc + col] = (__bf16)v;
        else          ((float*)C)[row * ldc + col] = v;
      }
    }
  }
}

// ---------------- V transpose: qkv v-slice (n, d) -> vt[(b,h,dk)][l] ----------
__global__ __launch_bounds__(256) void vtrans_kernel(
    const __bf16* __restrict__ qkv, __bf16* __restrict__ vt)
{
  __shared__ __bf16 t[64][66];
  const int tid = threadIdx.x;
  const int bh = blockIdx.x;           // b*16+h
  const int b = bh >> 4, h = bh & 15;
  const int l0 = blockIdx.y * 64;
  const int r4 = tid >> 6;             // 0..3
  const int c  = tid & 63;
#pragma unroll
  for (int rep = 0; rep < 16; ++rep) {
    int ll = rep * 4 + r4;
    t[ll][c] = qkv[(size_t)(b * SEQ + l0 + ll) * LDQKV + 2048 + h * DKH + c];
  }
  __syncthreads();
#pragma unroll
  for (int rep = 0; rep < 16; ++rep) {
    int dk = rep * 4 + r4;
    vt[(size_t)(bh * DKH + dk) * SEQ + l0 + c] = t[c][dk];
  }
}

// ---------------- MFMA flash attention (causal, key-split) --------------------
// Block = 4 waves x 16 queries; K/V^T 64x64 tile SINGLE-buffered in LDS.
// RESIDENCY FIX (r5): ledger r1/r2/r4 shows the kernel is latency-bound at
// too-low wave residency, and LDS/block caps residency (40KB -> 4 blocks/CU,
// measured avg ~2). Dropping the K/V double buffer cuts LDS to 24KB -> 6
// blocks/CU (24 waves). Staging latency is now exposed within a block
// (stage -> barrier -> compute), but 6 co-resident independent blocks
// overlap each other's stalls — cross-block TLP replaces intra-block
// double-buffering. All fragment layouts/swizzles/mask logic byte-identical
// to the verified r0/r3/r4 code.
// Key-split schedule retained from r4 (it fills the 6 slots): units per bh,
// longest-first: u<32 -> half (u&1) of qs=31-(u>>1) (8..16 tiles, partial
// f32 out, combine-by-ADD since softmax has no running max); u>=32 -> single
// qb=47-u (16..1 tiles, direct bf16 out). Grid 32*48=1536 = 6/CU.
// S^T trick: compute K Q^T (swapped operands) so each lane holds 4 CONSECUTIVE
// keys for ONE query -> P repack is 4 packed ds_write_b64.
// Row-sums l via MFMA with ones-B: lands in C-layout rows, zero shuffles.
__global__ __launch_bounds__(256) void attn_kernel(
    const __bf16* __restrict__ qkv,   // [4096][3072]
    const __bf16* __restrict__ vt,    // [32*64][2048]
    __bf16* __restrict__ attn,        // [4096][1024]
    float* __restrict__ Opart,        // [32*16*2][64*64] f32 partial O
    float* __restrict__ lpart)        // [32*16*2][64]    f32 partial l
{
  __shared__ __bf16 sK[64 * 64];      // [key][dk], granule-swizzled
  __shared__ __bf16 sV[64 * 64];      // [dk][key], granule-swizzled
  __shared__ __bf16 pbuf[4][16 * 64]; // per-wave P, [q][k] XOR-granule swizzle
  const int tid  = threadIdx.x;
  const int wave = tid >> 6, lane = tid & 63;
  const int quad = lane >> 4, l16 = lane & 15;
  const int id = blockIdx.x;
  const int bh = id & 31;
  const int u  = id >> 5;            // 0..47, longest-first
  int qb, t_lo, t_hi, rec;
  if (u < 32) {                      // split halves of qs = 31-(u>>1)
    qb = 31 - (u >> 1);
    const int nh = (qb + 1) >> 1;
    const int half = u & 1;
    t_lo = half ? nh : 0;
    t_hi = half ? qb + 1 : nh;
    rec  = (bh * 16 + (qb - 16)) * 2 + half;
  } else {                           // singles qb = 15..0
    qb = 47 - u;
    t_lo = 0; t_hi = qb + 1; rec = -1;
  }
  const int b = bh >> 4, h = bh & 15;
  const int qw = qb * 64 + wave * 16;         // wave's first query row
  const size_t tokbase = (size_t)b * SEQ;

  // staging: lane l -> (row = l>>3, swizzled granule (l&7)^(l>>3))
  const int srow = lane >> 3;
  const int sgr  = (lane & 7) ^ srow;
  const __bf16* pKsrc = qkv + (tokbase + wave * 16 + srow) * LDQKV + 1024 + h * DKH + sgr * 8;
  const __bf16* pVsrc = vt + ((size_t)bh * DKH + wave * 16 + srow) * SEQ + sgr * 8;
  const int lo = wave * 16 * 64;              // wave's slab within buffer

  bf16x8 qf[2];
#pragma unroll
  for (int s = 0; s < 2; ++s)
    qf[s] = *(const bf16x8*)(qkv + (tokbase + qw + l16) * LDQKV + h * DKH + s * 32 + quad * 8);

  bf16x8 ones;
#pragma unroll
  for (int i = 0; i < 8; ++i) ones[i] = (__bf16)1.0f;

  f32x4 o[4], lacc;
  const f32x4 z = {0.f, 0.f, 0.f, 0.f};
#pragma unroll
  for (int t = 0; t < 4; ++t) o[t] = z;
  lacc = z;

  __bf16* pb = &pbuf[wave][0];
  const int swl = l16 & 7;   // K/V read-side swizzle key

  for (int t0 = t_lo; t0 < t_hi; ++t0) {
    __syncthreads();                 // all waves done reading previous tile
    {
      const size_t koff = (size_t)t0 * 64;
      async_copy16(pKsrc + koff * LDQKV, &sK[lo]);
      async_copy16(pKsrc + (koff + 8) * LDQKV, &sK[lo + 8 * 64]);
      async_copy16(pVsrc + koff, &sV[lo]);
      async_copy16(pVsrc + (size_t)8 * SEQ + koff, &sV[lo + 8 * 64]);
    }
    __syncthreads();                 // staging landed (vmcnt drained)

    // S^T = K Q^T : 4 row-tiles of 16 keys; lane holds keys ct*16+quad*4+r
    // for query l16 (C-layout with A=K, B=Q).
    f32x4 sacc[4];
#pragma unroll
    for (int ct = 0; ct < 4; ++ct) {
      bf16x8 k0 = *(const bf16x8*)(sK + (ct * 16 + l16) * 64 + ((quad ^ swl) * 8));
      bf16x8 k1 = *(const bf16x8*)(sK + (ct * 16 + l16) * 64 + (((4 + quad) ^ swl) * 8));
      sacc[ct] = MFMA_BF16(k0, qf[0], z);
      sacc[ct] = MFMA_BF16(k1, qf[1], sacc[ct]);
    }

    // P = exp2(S^T) -> packed bf16x4 -> per-wave LDS [q][k], XOR-swizzled
    // diagonal mask only at t0==qb (last tile of singles & split-halfB)
#pragma unroll
    for (int ct = 0; ct < 4; ++ct) {
      bf16x4 p4;
      if (t0 < qb) {
#pragma unroll
        for (int r = 0; r < 4; ++r) p4[r] = (__bf16)fast_exp2(sacc[ct][r]);
      } else {
#pragma unroll
        for (int r = 0; r < 4; ++r) {
          float sv = (ct * 16 + quad * 4 + r <= wave * 16 + l16) ? sacc[ct][r] : -1e30f;
          p4[r] = (__bf16)fast_exp2(sv);
        }
      }
      *(bf16x4*)(pb + l16 * 64 + (((ct * 4 + quad) ^ (swl << 1)) * 4)) = p4;
    }
    // A-layout fragments: 16B granule-pair t = quad+4h, swizzled by q&7
    bf16x8 ap0 = *(const bf16x8*)(pb + l16 * 64 + ((quad ^ swl) * 8));
    bf16x8 ap1 = *(const bf16x8*)(pb + l16 * 64 + (((4 + quad) ^ swl) * 8));

    // l += P * 1 (row sums in C-layout: row quad*4+r = query — no shuffles)
    lacc = MFMA_BF16(ap0, ones, lacc);
    lacc = MFMA_BF16(ap1, ones, lacc);

    // O += P V : 4 dk-tiles
#pragma unroll
    for (int dt = 0; dt < 4; ++dt) {
      bf16x8 v0 = *(const bf16x8*)(sV + (dt * 16 + l16) * 64 + ((quad ^ swl) * 8));
      bf16x8 v1 = *(const bf16x8*)(sV + (dt * 16 + l16) * 64 + (((4 + quad) ^ swl) * 8));
      o[dt] = MFMA_BF16(ap0, v0, o[dt]);
      o[dt] = MFMA_BF16(ap1, v1, o[dt]);
    }
  }

  if (rec < 0) {
    // direct output: full key range was processed in this block
    float linv[4];
#pragma unroll
    for (int r = 0; r < 4; ++r) linv[r] = 1.0f / lacc[r];
#pragma unroll
    for (int dt = 0; dt < 4; ++dt)
#pragma unroll
      for (int r = 0; r < 4; ++r)
        attn[(tokbase + qw + quad * 4 + r) * DMODEL + h * DKH + dt * 16 + l16] =
            (__bf16)(o[dt][r] * linv[r]);
  } else {
    // partial output: raw f32 O and l, combined by combine_kernel
    float* Op = Opart + (size_t)rec * 4096;
#pragma unroll
    for (int dt = 0; dt < 4; ++dt)
#pragma unroll
      for (int r = 0; r < 4; ++r)
        Op[(wave * 16 + quad * 4 + r) * 64 + dt * 16 + l16] = o[dt][r];
    if (l16 == 0) {
#pragma unroll
      for (int r = 0; r < 4; ++r)
        lpart[rec * 64 + wave * 16 + quad * 4 + r] = lacc[r];
    }
  }
}

// ---------------- combine: sum split-half partials, divide, write bf16 --------
__global__ __launch_bounds__(256) void combine_kernel(
    const float* __restrict__ Opart, const float* __restrict__ lpart,
    __bf16* __restrict__ attn)
{
  const int blk = blockIdx.x;          // 512 = bh*16 + (qs-16)
  const int bh = blk >> 4, qs = 16 + (blk & 15);
  const int b = bh >> 4, h = bh & 15;
  const int tid = threadIdx.x;
  const int q  = tid >> 2;             // 0..63 query within tile
  const int d0 = (tid & 3) * 16;       // dk base
  const int recA = blk * 2, recB = recA + 1;
  const float lsum = lpart[recA * 64 + q] + lpart[recB * 64 + q];
  const float linv = 1.0f / lsum;
  const float4* OA = (const float4*)(Opart + (size_t)recA * 4096 + q * 64 + d0);
  const float4* OB = (const float4*)(Opart + (size_t)recB * 4096 + q * 64 + d0);
  const size_t tok = (size_t)b * SEQ + qs * 64 + q;
  __bf16* dst = attn + tok * DMODEL + h * DKH + d0;
#pragma unroll
  for (int j = 0; j < 4; ++j) {
    float4 a = OA[j], c = OB[j];
    bf16x4 o4;
    o4[0] = (__bf16)((a.x + c.x) * linv);
    o4[1] = (__bf16)((a.y + c.y) * linv);
    o4[2] = (__bf16)((a.z + c.z) * linv);
    o4[3] = (__bf16)((a.w + c.w) * linv);
    *(bf16x4*)(dst + j * 4) = o4;
  }
}

// ---------------- launch ------------------------------------------------------
extern "C" void kernel_launch(void* const* d_in, const int* in_sizes, int n_in,
                              void* d_out, int out_size, void* d_ws, size_t ws_size,
                              hipStream_t stream) {
  const float* x  = (const float*)d_in[0];
  const float* wq = (const float*)d_in[1];
  const float* bq = (const float*)d_in[2];
  const float* wk = (const float*)d_in[3];
  const float* bk = (const float*)d_in[4];
  const float* wv = (const float*)d_in[5];
  const float* bv = (const float*)d_in[6];
  const float* wo = (const float*)d_in[7];
  const float* bo = (const float*)d_in[8];

  char* ws = (char*)d_ws;
  __bf16* xb    = (__bf16*)(ws + 0);
  __bf16* wqkv  = (__bf16*)(ws + 8388608);
  __bf16* wob   = (__bf16*)(ws + 14680064);
  float*  bcat  = (float*)(ws + 16777216);
  __bf16* qkv   = (__bf16*)(ws + 16789504);
  __bf16* vt    = (__bf16*)(ws + 41955328);
  __bf16* attn  = (__bf16*)(ws + 50343936);
  float*  Opart = (float*)(ws + 67108864);   // 16 MiB: 1024 recs x 4096 f32
  float*  lpart = (float*)(ws + 83886080);   // 256 KiB: 1024 recs x 64 f32
  float*  out   = (float*)d_out;

  pack_kernel<<<1024, 256, 0, stream>>>(
      (const float4*)x, (const float4*)wq, (const float4*)wk, (const float4*)wv,
      (const float4*)wo, (const float4*)bq, (const float4*)bk, (const float4*)bv,
      (bf16x4*)xb, (bf16x4*)wqkv, (bf16x4*)wob, (float4*)bcat);

  // fused QKV projection: M=4096, N=3072, K=1024
  gemm_bias<128><<<dim3(32, 24), 256, 0, stream>>>(xb, wqkv, bcat, qkv, LDQKV, 1);

  vtrans_kernel<<<dim3(32, 32), 256, 0, stream>>>(qkv, vt);

  // flash attention: 1536 key-split blocks (<=16 tiles each, LPT order),
  // 24KB LDS -> 6 blocks/CU
  attn_kernel<<<1536, 256, 0, stream>>>(qkv, vt, attn, Opart, lpart);

  // combine split-half partials for q-tiles 16..31
  combine_kernel<<<512, 256, 0, stream>>>(Opart, lpart, attn);

  // output projection: M=4096, N=1024, K=1024, 128x64 tiles (512 blocks)
  gemm_bias<64><<<dim3(32, 16), 256, 0, stream>>>(attn, wob, bo, out, DMODEL, 0);
}

// Round 6
// 179.442 us; speedup vs baseline: 1.0532x; 1.0532x over previous
//
#include <hip/hip_runtime.h>
#include <cstdint>

// Problem constants: B=2, L=2048, D=1024, H=16, DK=64
#define SEQ     2048
#define DMODEL  1024
#define NHEAD   16
#define DKH     64
#define NTOK    4096      // B*L
#define LDQKV   3072      // qkv buffer row stride (q|k|v)

typedef __bf16 bf16x8 __attribute__((ext_vector_type(8)));
typedef __bf16 bf16x4 __attribute__((ext_vector_type(4)));
typedef float  f32x4  __attribute__((ext_vector_type(4)));

#define MFMA_BF16(a, b, c) __builtin_amdgcn_mfma_f32_16x16x32_bf16((a), (b), (c), 0, 0, 0)

// 0.125 * log2(e): folded into wq/bq at pack time. Softmax shift dropped
// entirely — exp2(s) scales O and l identically, cancels in O/l.
#define C2F 0.18033688f

__device__ inline float fast_exp2(float x) {
#if __has_builtin(__builtin_amdgcn_exp2f)
  return __builtin_amdgcn_exp2f(x);
#else
  return __expf(x * 0.69314718056f);
#endif
}

// async global->LDS copy, 16B per lane; LDS dest is wave-uniform base + lane*16
__device__ inline void async_copy16(const void* g, void* l) {
  __builtin_amdgcn_global_load_lds(
      reinterpret_cast<const __attribute__((address_space(1))) void*>(
          reinterpret_cast<uintptr_t>(g)),
      reinterpret_cast<__attribute__((address_space(3))) void*>(
          reinterpret_cast<uintptr_t>(l)),
      16, 0, 0);
}

__device__ inline bf16x4 cvt4(float4 v) {
  bf16x4 r;
  r[0] = (__bf16)v.x; r[1] = (__bf16)v.y; r[2] = (__bf16)v.z; r[3] = (__bf16)v.w;
  return r;
}

// ---------------- pack: fp32 -> bf16 casts + weight/bias concat ----------------
__global__ __launch_bounds__(256) void pack_kernel(
    const float4* __restrict__ x,
    const float4* __restrict__ wq, const float4* __restrict__ wk,
    const float4* __restrict__ wv, const float4* __restrict__ wo,
    const float4* __restrict__ bq, const float4* __restrict__ bk,
    const float4* __restrict__ bv,
    bf16x4* __restrict__ xb, bf16x4* __restrict__ wqkv,
    bf16x4* __restrict__ wob, float4* __restrict__ bcat)
{
  const int NX = NTOK * DMODEL / 4;       // 1048576 float4 groups of x
  const int NW = DMODEL * DMODEL / 4;     // 262144 per weight
  const int TOT = NX + 4 * NW + 3 * (DMODEL / 4);
  for (int g = blockIdx.x * 256 + threadIdx.x; g < TOT; g += gridDim.x * 256) {
    if (g < NX) {
      xb[g] = cvt4(x[g]);
    } else if (g < NX + 3 * NW) {
      int g2 = g - NX;
      const float4* s = (g2 < NW) ? wq : (g2 < 2 * NW ? wk : wv);
      float4 v = s[g2 & (NW - 1)];
      if (g2 < NW) { v.x *= C2F; v.y *= C2F; v.z *= C2F; v.w *= C2F; }
      wqkv[g2] = cvt4(v);
    } else if (g < NX + 4 * NW) {
      int g3 = g - NX - 3 * NW;
      wob[g3] = cvt4(wo[g3]);
    } else {
      int g4 = g - NX - 4 * NW;
      const float4* s = (g4 < 256) ? bq : (g4 < 512 ? bk : bv);
      float4 v = s[g4 & 255];
      if (g4 < 256) { v.x *= C2F; v.y *= C2F; v.z *= C2F; v.w *= C2F; }
      bcat[g4] = v;
    }
  }
}

// ---------------- QKV GEMM, 256x256 tile, BK=64, 8 waves, phase-split ---------
// C[4096,3072] = A[4096,1024] * W[3072,1024]^T + bias, bf16 out.
// Structure per guide's verified 256^2 template class: 512 threads (2Mx4N
// waves, each owns 128x64 of C), 128KB LDS (2 K-tile buffers), per K-tile
// 4 phases x 16 MFMA with raw s_barrier fences + setprio(1) around MFMA.
// Full next-tile staging (8 global_load_lds/thread) issued at phase 1 ->
// issue-to-wait distance ~4 phases (>700cyc >> L2 latency), so the single
// boundary vmcnt(0) is near-free (T4's mechanism with only 2 buffers).
// Staging/read swizzle pair is the attn kernel's verified idiom: 8-row
// chunks, source granule (lane&7)^(lane>>3), reads at (quad^swl)*8 and
// ((4+quad)^swl)*8 — 2-way (free) bank aliasing within quarter-waves.
// Race-freedom: reads of buf[cur] are register-complete before each wave's
// boundary-barrier arrival; staging always targets the other buffer.
__global__ __launch_bounds__(512, 2) void gemm_qkv_256(
    const __bf16* __restrict__ A,    // xb  [4096][1024]
    const __bf16* __restrict__ W,    // wqkv [3072][1024]
    const float* __restrict__ bias,  // bcat [3072]
    __bf16* __restrict__ C)          // qkv [4096][3072]
{
  constexpr int K = 1024;
  __shared__ __bf16 sA[2][256 * 64];  // 32KB each
  __shared__ __bf16 sB[2][256 * 64];
  const int tid  = threadIdx.x;
  const int wave = tid >> 6, lane = tid & 63;
  const int quad = lane >> 4, l16 = lane & 15;
  const int wm = wave >> 2, wn = wave & 3;     // 2 x 4 wave grid
  const int swl = l16 & 7;
  const size_t m0 = (size_t)blockIdx.x * 256;
  const size_t n0 = (size_t)blockIdx.y * 256;

  // staging bases: lane -> (row = chunk*8 + lane>>3, LDS granule lane&7,
  // source granule pre-swizzled by row&7)
  const int srow = lane >> 3;
  const int sgr  = (lane & 7) ^ srow;
  const __bf16* pA = A + (m0 + srow) * K + sgr * 8;
  const __bf16* pB = W + (n0 + srow) * K + sgr * 8;

  f32x4 acc[8][4];
  const f32x4 z = {0.f, 0.f, 0.f, 0.f};
#pragma unroll
  for (int i = 0; i < 8; ++i)
#pragma unroll
    for (int j = 0; j < 4; ++j) acc[i][j] = z;

#define STAGE_QKV(buf, k0)                                                    \
  {                                                                           \
    _Pragma("unroll")                                                         \
    for (int L = 0; L < 4; ++L) {                                             \
      const int c = L * 8 + wave;    /* chunk 0..31 = 8 rows each */          \
      async_copy16(pA + (size_t)(c * 8) * K + (k0), &sA[buf][c * 512]);       \
      async_copy16(pB + (size_t)(c * 8) * K + (k0), &sB[buf][c * 512]);       \
    }                                                                         \
  }

  int cur = 0;
  STAGE_QKV(0, 0);
  __syncthreads();                   // vmcnt(0) drain: tile 0 landed

  for (int t = 0; t < 16; ++t) {
    const __bf16* A_ = &sA[cur][0];
    const __bf16* B_ = &sB[cur][0];
    if (t + 1 < 16) STAGE_QKV(cur ^ 1, (t + 1) * 64);   // earliest issue

    bf16x8 af[4][2], bw0[2][2], bw1[2][2];
    // ---- phase 1: A rows 0..63 of wave + B cols 0..31; acc[0..3][0..1]
#pragma unroll
    for (int i = 0; i < 4; ++i) {
      const __bf16* r = A_ + (wm * 128 + i * 16 + l16) * 64;
      af[i][0] = *(const bf16x8*)(r + ((quad ^ swl) * 8));
      af[i][1] = *(const bf16x8*)(r + (((4 + quad) ^ swl) * 8));
    }
#pragma unroll
    for (int j = 0; j < 2; ++j) {
      const __bf16* r = B_ + (wn * 64 + j * 16 + l16) * 64;
      bw0[j][0] = *(const bf16x8*)(r + ((quad ^ swl) * 8));
      bw0[j][1] = *(const bf16x8*)(r + (((4 + quad) ^ swl) * 8));
    }
    __builtin_amdgcn_s_setprio(1);
#pragma unroll
    for (int i = 0; i < 4; ++i)
#pragma unroll
      for (int j = 0; j < 2; ++j) {
        acc[i][j] = MFMA_BF16(af[i][0], bw0[j][0], acc[i][j]);
        acc[i][j] = MFMA_BF16(af[i][1], bw0[j][1], acc[i][j]);
      }
    __builtin_amdgcn_s_setprio(0);
    __builtin_amdgcn_s_barrier();

    // ---- phase 2: B cols 32..63; acc[0..3][2..3]
#pragma unroll
    for (int j = 0; j < 2; ++j) {
      const __bf16* r = B_ + (wn * 64 + 32 + j * 16 + l16) * 64;
      bw1[j][0] = *(const bf16x8*)(r + ((quad ^ swl) * 8));
      bw1[j][1] = *(const bf16x8*)(r + (((4 + quad) ^ swl) * 8));
    }
    __builtin_amdgcn_s_setprio(1);
#pragma unroll
    for (int i = 0; i < 4; ++i)
#pragma unroll
      for (int j = 0; j < 2; ++j) {
        acc[i][2 + j] = MFMA_BF16(af[i][0], bw1[j][0], acc[i][2 + j]);
        acc[i][2 + j] = MFMA_BF16(af[i][1], bw1[j][1], acc[i][2 + j]);
      }
    __builtin_amdgcn_s_setprio(0);
    __builtin_amdgcn_s_barrier();

    // ---- phase 3: A rows 64..127 of wave (overwrite af); acc[4..7][2..3]
#pragma unroll
    for (int i = 0; i < 4; ++i) {
      const __bf16* r = A_ + (wm * 128 + 64 + i * 16 + l16) * 64;
      af[i][0] = *(const bf16x8*)(r + ((quad ^ swl) * 8));
      af[i][1] = *(const bf16x8*)(r + (((4 + quad) ^ swl) * 8));
    }
    __builtin_amdgcn_s_setprio(1);
#pragma unroll
    for (int i = 0; i < 4; ++i)
#pragma unroll
      for (int j = 0; j < 2; ++j) {
        acc[4 + i][2 + j] = MFMA_BF16(af[i][0], bw1[j][0], acc[4 + i][2 + j]);
        acc[4 + i][2 + j] = MFMA_BF16(af[i][1], bw1[j][1], acc[4 + i][2 + j]);
      }
    __builtin_amdgcn_s_setprio(0);
    __builtin_amdgcn_s_barrier();

    // ---- phase 4: acc[4..7][0..1] (bw0 still live); boundary
    __builtin_amdgcn_s_setprio(1);
#pragma unroll
    for (int i = 0; i < 4; ++i)
#pragma unroll
      for (int j = 0; j < 2; ++j) {
        acc[4 + i][j] = MFMA_BF16(af[i][0], bw0[j][0], acc[4 + i][j]);
        acc[4 + i][j] = MFMA_BF16(af[i][1], bw0[j][1], acc[4 + i][j]);
      }
    __builtin_amdgcn_s_setprio(0);
    asm volatile("s_waitcnt vmcnt(0)" ::: "memory");  // next tile landed
    __builtin_amdgcn_s_barrier();
    cur ^= 1;
  }
#undef STAGE_QKV

  float bi[4];
#pragma unroll
  for (int jj = 0; jj < 4; ++jj)
    bi[jj] = bias[n0 + wn * 64 + (jj >> 1) * 32 + (jj & 1) * 16 + l16];

#pragma unroll
  for (int i = 0; i < 8; ++i)
#pragma unroll
    for (int jj = 0; jj < 4; ++jj)
#pragma unroll
      for (int r = 0; r < 4; ++r) {
        size_t row = m0 + wm * 128 + i * 16 + quad * 4 + r;
        size_t col = n0 + wn * 64 + (jj >> 1) * 32 + (jj & 1) * 16 + l16;
        C[row * LDQKV + col] = (__bf16)(acc[i][jj][r] + bi[jj]);
      }
}

// ---------------- GEMM: C[M,N] = A[M,K] * W[N,K]^T + bias, K=1024 -------------
// 128xBN tile (BN=128 or 64), double-buffered LDS staging. (out-proj)
template<int BN>
__global__ __launch_bounds__(256) void gemm_bias(
    const __bf16* __restrict__ A, const __bf16* __restrict__ W,
    const float* __restrict__ bias, void* __restrict__ C,
    int ldc, int out_bf16)
{
  constexpr int K = 1024;
  constexpr int JT = BN / 32;          // j-tiles per wave: 4 or 2
  __shared__ __bf16 sA[2][128 * 32];
  __shared__ __bf16 sB[2][BN * 32];
  const int tid  = threadIdx.x;
  const int wave = tid >> 6, lane = tid & 63;
  const int quad = lane >> 4, l16 = lane & 15;
  const size_t m0 = (size_t)blockIdx.x * 128;
  const size_t n0 = (size_t)blockIdx.y * BN;
  const int wm = (wave & 1) * 64, wn = (wave >> 1) * (BN / 2);

  const int g0 = wave * 2;
  const int sr = lane >> 2;          // row within 16-row group
  const int sc = (lane & 3) * 8;     // bf16 col offset within BK=32
  const __bf16* pa0 = A + (m0 + g0 * 16 + sr) * K + sc;
  const __bf16* pa1 = pa0 + 16 * K;
  const int brow = (BN == 128) ? g0 * 16 : wave * 16;
  const __bf16* pb0 = W + (n0 + brow + sr) * K + sc;
  const int lo  = g0 * 512;
  const int lob = (BN == 128) ? g0 * 512 : wave * 512;

  f32x4 acc[4][JT];
  const f32x4 z = {0.f, 0.f, 0.f, 0.f};
#pragma unroll
  for (int i = 0; i < 4; ++i)
#pragma unroll
    for (int j = 0; j < JT; ++j) acc[i][j] = z;

  // prologue: stage k0=0 into buffer 0
  async_copy16(pa0, &sA[0][lo]);
  async_copy16(pa1, &sA[0][lo + 512]);
  async_copy16(pb0, &sB[0][lob]);
  if (BN == 128) async_copy16(pb0 + 16 * K, &sB[0][lob + 512]);

  for (int k0 = 0; k0 < K; k0 += 32) {
    const int cur = (k0 >> 5) & 1, nxt = cur ^ 1;
    __syncthreads();                 // tile k0 staged; prev reads of nxt done
    if (k0 + 32 < K) {
      async_copy16(pa0 + k0 + 32, &sA[nxt][lo]);
      async_copy16(pa1 + k0 + 32, &sA[nxt][lo + 512]);
      async_copy16(pb0 + k0 + 32, &sB[nxt][lob]);
      if (BN == 128) async_copy16(pb0 + 16 * K + k0 + 32, &sB[nxt][lob + 512]);
    }

    bf16x8 af[4], bw[JT];
#pragma unroll
    for (int i = 0; i < 4; ++i)
      af[i] = *(const bf16x8*)(&sA[cur][(wm + i * 16 + l16) * 32 + quad * 8]);
#pragma unroll
    for (int j = 0; j < JT; ++j)
      bw[j] = *(const bf16x8*)(&sB[cur][(wn + j * 16 + l16) * 32 + quad * 8]);
#pragma unroll
    for (int i = 0; i < 4; ++i)
#pragma unroll
      for (int j = 0; j < JT; ++j)
        acc[i][j] = MFMA_BF16(af[i], bw[j], acc[i][j]);
  }

  float bi[JT];
#pragma unroll
  for (int j = 0; j < JT; ++j) bi[j] = bias[n0 + wn + j * 16 + l16];

#pragma unroll
  for (int i = 0; i < 4; ++i) {
#pragma unroll
    for (int j = 0; j < JT; ++j) {
#pragma unroll
      for (int r = 0; r < 4; ++r) {
        size_t row = m0 + wm + i * 16 + quad * 4 + r;
        size_t col = n0 + wn + j * 16 + l16;
        float v = acc[i][j][r] + bi[j];
        if (out_bf16) ((__bf16*)C)[row * ldc + col] = (__bf16)v;
        else          ((float*)C)[row * ldc + col] = v;
      }
    }
  }
}

// ---------------- V transpose: qkv v-slice (n, d) -> vt[(b,h,dk)][l] ----------
__global__ __launch_bounds__(256) void vtrans_kernel(
    const __bf16* __restrict__ qkv, __bf16* __restrict__ vt)
{
  __shared__ __bf16 t[64][66];
  const int tid = threadIdx.x;
  const int bh = blockIdx.x;           // b*16+h
  const int b = bh >> 4, h = bh & 15;
  const int l0 = blockIdx.y * 64;
  const int r4 = tid >> 6;             // 0..3
  const int c  = tid & 63;
#pragma unroll
  for (int rep = 0; rep < 16; ++rep) {
    int ll = rep * 4 + r4;
    t[ll][c] = qkv[(size_t)(b * SEQ + l0 + ll) * LDQKV + 2048 + h * DKH + c];
  }
  __syncthreads();
#pragma unroll
  for (int rep = 0; rep < 16; ++rep) {
    int dk = rep * 4 + r4;
    vt[(size_t)(bh * DKH + dk) * SEQ + l0 + c] = t[c][dk];
  }
}

// ---------------- MFMA flash attention (causal) -------------------------------
// r3's exact verified kernel (42.8us measured): 4 waves x 16 queries,
// K/V^T 64x64 tiles double-buffered, balanced-qb swizzle, setprio on MFMA.
__global__ __launch_bounds__(256) void attn_kernel(
    const __bf16* __restrict__ qkv,   // [4096][3072]
    const __bf16* __restrict__ vt,    // [32*64][2048]
    __bf16* __restrict__ attn)        // [4096][1024]
{
  __shared__ __bf16 sK[2][64 * 64];   // [key][dk], granule-swizzled
  __shared__ __bf16 sV[2][64 * 64];   // [dk][key], granule-swizzled
  __shared__ __bf16 pbuf[4][16 * 64]; // per-wave P, [q][k] XOR-granule swizzle
  const int tid  = threadIdx.x;
  const int wave = tid >> 6, lane = tid & 63;
  const int quad = lane >> 4, l16 = lane & 15;
  const int id = blockIdx.x;
  const int u = (id >> 3) & 31, v = id & 7, w = id >> 8;
  const int bh = v * 4 + w;
  const int ue = u ^ ((w >> 1) << 3);         // temporal mix across the CU's 4 blocks
  const int qb = (w & 1) ? ue : 31 - ue;
  const int b = bh >> 4, h = bh & 15;
  const int q0 = qb * 64;
  const int qw = q0 + wave * 16;              // wave's first query row
  const size_t tokbase = (size_t)b * SEQ;

  // staging: lane l -> (row = l>>3, swizzled granule (l&7)^(l>>3))
  const int srow = lane >> 3;
  const int sgr  = (lane & 7) ^ srow;
  const __bf16* pKsrc = qkv + (tokbase + wave * 16 + srow) * LDQKV + 1024 + h * DKH + sgr * 8;
  const __bf16* pVsrc = vt + ((size_t)bh * DKH + wave * 16 + srow) * SEQ + sgr * 8;
  const int lo = wave * 16 * 64;              // wave's slab within buffer

  bf16x8 qf[2];
#pragma unroll
  for (int s = 0; s < 2; ++s)
    qf[s] = *(const bf16x8*)(qkv + (tokbase + qw + l16) * LDQKV + h * DKH + s * 32 + quad * 8);

  bf16x8 ones;
#pragma unroll
  for (int i = 0; i < 8; ++i) ones[i] = (__bf16)1.0f;

  f32x4 o[4], lacc;
  const f32x4 z = {0.f, 0.f, 0.f, 0.f};
#pragma unroll
  for (int t = 0; t < 4; ++t) o[t] = z;
  lacc = z;

  __bf16* pb = &pbuf[wave][0];
  const int swl = l16 & 7;   // K/V read-side swizzle key

  // prologue: stage key-tile 0 into buffer 0
  async_copy16(pKsrc, &sK[0][lo]);
  async_copy16(pKsrc + (size_t)8 * LDQKV, &sK[0][lo + 8 * 64]);
  async_copy16(pVsrc, &sV[0][lo]);
  async_copy16(pVsrc + (size_t)8 * SEQ, &sV[0][lo + 8 * 64]);

  for (int t0 = 0; t0 <= qb; ++t0) {
    const int cur = t0 & 1, nxt = cur ^ 1;
    __syncthreads();                 // tile t0 staged; prev reads of nxt done
    if (t0 < qb) {
      const size_t koff = (size_t)(t0 + 1) * 64;
      async_copy16(pKsrc + koff * LDQKV, &sK[nxt][lo]);
      async_copy16(pKsrc + (koff + 8) * LDQKV, &sK[nxt][lo + 8 * 64]);
      async_copy16(pVsrc + koff, &sV[nxt][lo]);
      async_copy16(pVsrc + (size_t)8 * SEQ + koff, &sV[nxt][lo + 8 * 64]);
    }
    const __bf16* K_ = &sK[cur][0];
    const __bf16* V_ = &sV[cur][0];

    // S^T = K Q^T : 4 row-tiles of 16 keys; lane holds keys ct*16+quad*4+r
    // for query l16 (C-layout with A=K, B=Q).
    f32x4 sacc[4];
    __builtin_amdgcn_s_setprio(1);
#pragma unroll
    for (int ct = 0; ct < 4; ++ct) {
      bf16x8 k0 = *(const bf16x8*)(K_ + (ct * 16 + l16) * 64 + ((quad ^ swl) * 8));
      bf16x8 k1 = *(const bf16x8*)(K_ + (ct * 16 + l16) * 64 + (((4 + quad) ^ swl) * 8));
      sacc[ct] = MFMA_BF16(k0, qf[0], z);
      sacc[ct] = MFMA_BF16(k1, qf[1], sacc[ct]);
    }
    __builtin_amdgcn_s_setprio(0);

    // P = exp2(S^T) -> packed bf16x4 -> per-wave LDS [q][k], XOR-swizzled
#pragma unroll
    for (int ct = 0; ct < 4; ++ct) {
      bf16x4 p4;
      if (t0 < qb) {
#pragma unroll
        for (int r = 0; r < 4; ++r) p4[r] = (__bf16)fast_exp2(sacc[ct][r]);
      } else {
#pragma unroll
        for (int r = 0; r < 4; ++r) {
          float sv = (ct * 16 + quad * 4 + r <= wave * 16 + l16) ? sacc[ct][r] : -1e30f;
          p4[r] = (__bf16)fast_exp2(sv);
        }
      }
      *(bf16x4*)(pb + l16 * 64 + (((ct * 4 + quad) ^ (swl << 1)) * 4)) = p4;
    }
    // A-layout fragments: 16B granule-pair t = quad+4h, swizzled by q&7
    bf16x8 ap0 = *(const bf16x8*)(pb + l16 * 64 + ((quad ^ swl) * 8));
    bf16x8 ap1 = *(const bf16x8*)(pb + l16 * 64 + (((4 + quad) ^ swl) * 8));

    __builtin_amdgcn_s_setprio(1);
    // l += P * 1 (row sums in C-layout: row quad*4+r = query — no shuffles)
    lacc = MFMA_BF16(ap0, ones, lacc);
    lacc = MFMA_BF16(ap1, ones, lacc);

    // O += P V : 4 dk-tiles
#pragma unroll
    for (int dt = 0; dt < 4; ++dt) {
      bf16x8 v0 = *(const bf16x8*)(V_ + (dt * 16 + l16) * 64 + ((quad ^ swl) * 8));
      bf16x8 v1 = *(const bf16x8*)(V_ + (dt * 16 + l16) * 64 + (((4 + quad) ^ swl) * 8));
      o[dt] = MFMA_BF16(ap0, v0, o[dt]);
      o[dt] = MFMA_BF16(ap1, v1, o[dt]);
    }
    __builtin_amdgcn_s_setprio(0);
  }

  float linv[4];
#pragma unroll
  for (int r = 0; r < 4; ++r) linv[r] = 1.0f / lacc[r];

#pragma unroll
  for (int dt = 0; dt < 4; ++dt)
#pragma unroll
    for (int r = 0; r < 4; ++r)
      attn[(tokbase + qw + quad * 4 + r) * DMODEL + h * DKH + dt * 16 + l16] =
          (__bf16)(o[dt][r] * linv[r]);
}

// ---------------- launch ------------------------------------------------------
extern "C" void kernel_launch(void* const* d_in, const int* in_sizes, int n_in,
                              void* d_out, int out_size, void* d_ws, size_t ws_size,
                              hipStream_t stream) {
  const float* x  = (const float*)d_in[0];
  const float* wq = (const float*)d_in[1];
  const float* bq = (const float*)d_in[2];
  const float* wk = (const float*)d_in[3];
  const float* bk = (const float*)d_in[4];
  const float* wv = (const float*)d_in[5];
  const float* bv = (const float*)d_in[6];
  const float* wo = (const float*)d_in[7];
  const float* bo = (const float*)d_in[8];

  char* ws = (char*)d_ws;
  __bf16* xb    = (__bf16*)(ws + 0);
  __bf16* wqkv  = (__bf16*)(ws + 8388608);
  __bf16* wob   = (__bf16*)(ws + 14680064);
  float*  bcat  = (float*)(ws + 16777216);
  __bf16* qkv   = (__bf16*)(ws + 16789504);
  __bf16* vt    = (__bf16*)(ws + 41955328);
  __bf16* attn  = (__bf16*)(ws + 50343936);
  float*  out   = (float*)d_out;

  pack_kernel<<<1024, 256, 0, stream>>>(
      (const float4*)x, (const float4*)wq, (const float4*)wk, (const float4*)wv,
      (const float4*)wo, (const float4*)bq, (const float4*)bk, (const float4*)bv,
      (bf16x4*)xb, (bf16x4*)wqkv, (bf16x4*)wob, (float4*)bcat);

  // fused QKV projection: M=4096, N=3072, K=1024, 256^2 phase-split kernel
  gemm_qkv_256<<<dim3(16, 12), 512, 0, stream>>>(xb, wqkv, bcat, qkv);

  vtrans_kernel<<<dim3(32, 32), 256, 0, stream>>>(qkv, vt);

  // flash attention: 1-D grid, balanced swizzle (r3 verified config)
  attn_kernel<<<1024, 256, 0, stream>>>(qkv, vt, attn);

  // output projection: M=4096, N=1024, K=1024, 128x64 tiles (512 blocks)
  gemm_bias<64><<<dim3(32, 16), 256, 0, stream>>>(attn, wob, bo, out, DMODEL, 0);
}

// Round 7
// 175.761 us; speedup vs baseline: 1.0753x; 1.0209x over previous
//
#include <hip/hip_runtime.h>
#include <cstdint>

// Problem constants: B=2, L=2048, D=1024, H=16, DK=64
#define SEQ     2048
#define DMODEL  1024
#define NHEAD   16
#define DKH     64
#define NTOK    4096      // B*L
#define LDQKV   3072      // qkv buffer row stride (q|k|v)

typedef __bf16 bf16x8 __attribute__((ext_vector_type(8)));
typedef __bf16 bf16x4 __attribute__((ext_vector_type(4)));
typedef float  f32x4  __attribute__((ext_vector_type(4)));

#define MFMA_BF16(a, b, c) __builtin_amdgcn_mfma_f32_16x16x32_bf16((a), (b), (c), 0, 0, 0)

// 0.125 * log2(e): folded into wq/bq at pack time. Softmax shift dropped
// entirely — exp2(s) scales O and l identically, cancels in O/l.
#define C2F 0.18033688f

__device__ inline float fast_exp2(float x) {
#if __has_builtin(__builtin_amdgcn_exp2f)
  return __builtin_amdgcn_exp2f(x);
#else
  return __expf(x * 0.69314718056f);
#endif
}

// async global->LDS copy, 16B per lane; LDS dest is wave-uniform base + lane*16
__device__ inline void async_copy16(const void* g, void* l) {
  __builtin_amdgcn_global_load_lds(
      reinterpret_cast<const __attribute__((address_space(1))) void*>(
          reinterpret_cast<uintptr_t>(g)),
      reinterpret_cast<__attribute__((address_space(3))) void*>(
          reinterpret_cast<uintptr_t>(l)),
      16, 0, 0);
}

__device__ inline bf16x4 cvt4(float4 v) {
  bf16x4 r;
  r[0] = (__bf16)v.x; r[1] = (__bf16)v.y; r[2] = (__bf16)v.z; r[3] = (__bf16)v.w;
  return r;
}

// ---------------- pack: fp32 -> bf16 casts + weight/bias concat ----------------
__global__ __launch_bounds__(256) void pack_kernel(
    const float4* __restrict__ x,
    const float4* __restrict__ wq, const float4* __restrict__ wk,
    const float4* __restrict__ wv, const float4* __restrict__ wo,
    const float4* __restrict__ bq, const float4* __restrict__ bk,
    const float4* __restrict__ bv,
    bf16x4* __restrict__ xb, bf16x4* __restrict__ wqkv,
    bf16x4* __restrict__ wob, float4* __restrict__ bcat)
{
  const int NX = NTOK * DMODEL / 4;       // 1048576 float4 groups of x
  const int NW = DMODEL * DMODEL / 4;     // 262144 per weight
  const int TOT = NX + 4 * NW + 3 * (DMODEL / 4);
  for (int g = blockIdx.x * 256 + threadIdx.x; g < TOT; g += gridDim.x * 256) {
    if (g < NX) {
      xb[g] = cvt4(x[g]);
    } else if (g < NX + 3 * NW) {
      int g2 = g - NX;
      const float4* s = (g2 < NW) ? wq : (g2 < 2 * NW ? wk : wv);
      float4 v = s[g2 & (NW - 1)];
      if (g2 < NW) { v.x *= C2F; v.y *= C2F; v.z *= C2F; v.w *= C2F; }
      wqkv[g2] = cvt4(v);
    } else if (g < NX + 4 * NW) {
      int g3 = g - NX - 3 * NW;
      wob[g3] = cvt4(wo[g3]);
    } else {
      int g4 = g - NX - 4 * NW;
      const float4* s = (g4 < 256) ? bq : (g4 < 512 ? bk : bv);
      float4 v = s[g4 & 255];
      if (g4 < 256) { v.x *= C2F; v.y *= C2F; v.z *= C2F; v.w *= C2F; }
      bcat[g4] = v;
    }
  }
}

// ---------------- QKV GEMM, 256x192 tile, BK=64, 8 waves, phase-split ---------
// C[4096,3072] = A[4096,1024] * W[3072,1024]^T + bias, bf16 out.
// GEOMETRY FIX (r7): r6's 256x256 tiling gave 192 blocks on 256 CUs — 25%
// of the chip idle ate the phase-split gain (measured neutral). 256x192
// tiles -> 16x16 = EXACTLY 256 blocks = 1/CU, zero idle, zero tail.
// All verified r6 idioms carried unchanged: stage in 8-row chunks with
// source granule (lane&7)^(lane>>3); reads at (quad^swl)*8 / ((4+quad)^swl)*8
// (row&7 == l16&7 holds: 48 % 8 == 0); raw s_barrier phases + setprio(1)
// around MFMA; full next-tile staging issued at tile start, single boundary
// vmcnt(0) (issue-to-drain ~ a full tile of compute >> L2 latency).
// Per wave (2Mx4N grid): 128x48 of C, acc[8][3], 2 phases x 24 MFMA/tile.
// LDS 112KB (2 buffers of 56KB). Per-tile: stage 56KB (~1000cyc at L2 BW)
// vs 384 MFMA/CU (~1860cyc) -> compute-bound with margin.
// XCD chunk map: bid&7 = XCD (round-robin dispatch), each XCD gets a 4x8
// tile-rect (A 2MB + W 3MB ~ its 4MB L2). Bijective.
__global__ __launch_bounds__(512, 2) void gemm_qkv_256x192(
    const __bf16* __restrict__ A,    // xb  [4096][1024]
    const __bf16* __restrict__ W,    // wqkv [3072][1024]
    const float* __restrict__ bias,  // bcat [3072]
    __bf16* __restrict__ C)          // qkv [4096][3072]
{
  constexpr int K = 1024;
  __shared__ __bf16 sA[2][256 * 64];  // 32KB each
  __shared__ __bf16 sB[2][192 * 64];  // 24KB each
  const int tid  = threadIdx.x;
  const int wave = tid >> 6, lane = tid & 63;
  const int quad = lane >> 4, l16 = lane & 15;
  const int wm = wave >> 2, wn = wave & 3;     // 2 x 4 wave grid
  const int swl = l16 & 7;
  const int bid = blockIdx.x;
  const int xcd = bid & 7, slot = bid >> 3;
  const int mt = (xcd >> 1) * 4 + (slot >> 3);   // 0..15
  const int nt = (xcd & 1) * 8 + (slot & 7);     // 0..15
  const size_t m0 = (size_t)mt * 256;
  const size_t n0 = (size_t)nt * 192;

  // staging bases: lane -> (row = chunk*8 + lane>>3, LDS granule lane&7,
  // source granule pre-swizzled by row&7)
  const int srow = lane >> 3;
  const int sgr  = (lane & 7) ^ srow;
  const __bf16* pA = A + (m0 + srow) * K + sgr * 8;
  const __bf16* pB = W + (n0 + srow) * K + sgr * 8;

  f32x4 acc[8][3];
  const f32x4 z = {0.f, 0.f, 0.f, 0.f};
#pragma unroll
  for (int i = 0; i < 8; ++i)
#pragma unroll
    for (int j = 0; j < 3; ++j) acc[i][j] = z;

#define STAGE_QKV(buf, k0)                                                    \
  {                                                                           \
    _Pragma("unroll")                                                         \
    for (int L = 0; L < 4; ++L) {          /* A: 32 chunks of 8 rows */       \
      const int c = L * 8 + wave;                                             \
      async_copy16(pA + (size_t)(c * 8) * K + (k0), &sA[buf][c * 512]);       \
    }                                                                         \
    _Pragma("unroll")                                                         \
    for (int L = 0; L < 3; ++L) {          /* B: 24 chunks of 8 rows */       \
      const int c = L * 8 + wave;                                             \
      async_copy16(pB + (size_t)(c * 8) * K + (k0), &sB[buf][c * 512]);       \
    }                                                                         \
  }

  int cur = 0;
  STAGE_QKV(0, 0);
  __syncthreads();                   // vmcnt(0) drain: tile 0 landed

  for (int t = 0; t < 16; ++t) {
    const __bf16* A_ = &sA[cur][0];
    const __bf16* B_ = &sB[cur][0];
    if (t + 1 < 16) STAGE_QKV(cur ^ 1, (t + 1) * 64);   // earliest issue

    bf16x8 af[4][2], bw[3][2];
    // ---- phase 1: B cols (all 3 j) + A rows 0..63 of wave; acc[0..3][*]
#pragma unroll
    for (int j = 0; j < 3; ++j) {
      const __bf16* r = B_ + (wn * 48 + j * 16 + l16) * 64;
      bw[j][0] = *(const bf16x8*)(r + ((quad ^ swl) * 8));
      bw[j][1] = *(const bf16x8*)(r + (((4 + quad) ^ swl) * 8));
    }
#pragma unroll
    for (int i = 0; i < 4; ++i) {
      const __bf16* r = A_ + (wm * 128 + i * 16 + l16) * 64;
      af[i][0] = *(const bf16x8*)(r + ((quad ^ swl) * 8));
      af[i][1] = *(const bf16x8*)(r + (((4 + quad) ^ swl) * 8));
    }
    __builtin_amdgcn_s_setprio(1);
#pragma unroll
    for (int i = 0; i < 4; ++i)
#pragma unroll
      for (int j = 0; j < 3; ++j) {
        acc[i][j] = MFMA_BF16(af[i][0], bw[j][0], acc[i][j]);
        acc[i][j] = MFMA_BF16(af[i][1], bw[j][1], acc[i][j]);
      }
    __builtin_amdgcn_s_setprio(0);
    __builtin_amdgcn_s_barrier();

    // ---- phase 2: A rows 64..127 (overwrite af); acc[4..7][*]; boundary
#pragma unroll
    for (int i = 0; i < 4; ++i) {
      const __bf16* r = A_ + (wm * 128 + 64 + i * 16 + l16) * 64;
      af[i][0] = *(const bf16x8*)(r + ((quad ^ swl) * 8));
      af[i][1] = *(const bf16x8*)(r + (((4 + quad) ^ swl) * 8));
    }
    __builtin_amdgcn_s_setprio(1);
#pragma unroll
    for (int i = 0; i < 4; ++i)
#pragma unroll
      for (int j = 0; j < 3; ++j) {
        acc[4 + i][j] = MFMA_BF16(af[i][0], bw[j][0], acc[4 + i][j]);
        acc[4 + i][j] = MFMA_BF16(af[i][1], bw[j][1], acc[4 + i][j]);
      }
    __builtin_amdgcn_s_setprio(0);
    asm volatile("s_waitcnt vmcnt(0)" ::: "memory");  // next tile landed
    __builtin_amdgcn_s_barrier();
    cur ^= 1;
  }
#undef STAGE_QKV

  float bi[3];
#pragma unroll
  for (int j = 0; j < 3; ++j) bi[j] = bias[n0 + wn * 48 + j * 16 + l16];

#pragma unroll
  for (int i = 0; i < 8; ++i)
#pragma unroll
    for (int j = 0; j < 3; ++j)
#pragma unroll
      for (int r = 0; r < 4; ++r) {
        size_t row = m0 + wm * 128 + i * 16 + quad * 4 + r;
        size_t col = n0 + wn * 48 + j * 16 + l16;
        C[row * LDQKV + col] = (__bf16)(acc[i][j][r] + bi[j]);
      }
}

// ---------------- GEMM: C[M,N] = A[M,K] * W[N,K]^T + bias, K=1024 -------------
// 128xBN tile (BN=128 or 64), double-buffered LDS staging. (out-proj)
template<int BN>
__global__ __launch_bounds__(256) void gemm_bias(
    const __bf16* __restrict__ A, const __bf16* __restrict__ W,
    const float* __restrict__ bias, void* __restrict__ C,
    int ldc, int out_bf16)
{
  constexpr int K = 1024;
  constexpr int JT = BN / 32;          // j-tiles per wave: 4 or 2
  __shared__ __bf16 sA[2][128 * 32];
  __shared__ __bf16 sB[2][BN * 32];
  const int tid  = threadIdx.x;
  const int wave = tid >> 6, lane = tid & 63;
  const int quad = lane >> 4, l16 = lane & 15;
  const size_t m0 = (size_t)blockIdx.x * 128;
  const size_t n0 = (size_t)blockIdx.y * BN;
  const int wm = (wave & 1) * 64, wn = (wave >> 1) * (BN / 2);

  const int g0 = wave * 2;
  const int sr = lane >> 2;          // row within 16-row group
  const int sc = (lane & 3) * 8;     // bf16 col offset within BK=32
  const __bf16* pa0 = A + (m0 + g0 * 16 + sr) * K + sc;
  const __bf16* pa1 = pa0 + 16 * K;
  const int brow = (BN == 128) ? g0 * 16 : wave * 16;
  const __bf16* pb0 = W + (n0 + brow + sr) * K + sc;
  const int lo  = g0 * 512;
  const int lob = (BN == 128) ? g0 * 512 : wave * 512;

  f32x4 acc[4][JT];
  const f32x4 z = {0.f, 0.f, 0.f, 0.f};
#pragma unroll
  for (int i = 0; i < 4; ++i)
#pragma unroll
    for (int j = 0; j < JT; ++j) acc[i][j] = z;

  // prologue: stage k0=0 into buffer 0
  async_copy16(pa0, &sA[0][lo]);
  async_copy16(pa1, &sA[0][lo + 512]);
  async_copy16(pb0, &sB[0][lob]);
  if (BN == 128) async_copy16(pb0 + 16 * K, &sB[0][lob + 512]);

  for (int k0 = 0; k0 < K; k0 += 32) {
    const int cur = (k0 >> 5) & 1, nxt = cur ^ 1;
    __syncthreads();                 // tile k0 staged; prev reads of nxt done
    if (k0 + 32 < K) {
      async_copy16(pa0 + k0 + 32, &sA[nxt][lo]);
      async_copy16(pa1 + k0 + 32, &sA[nxt][lo + 512]);
      async_copy16(pb0 + k0 + 32, &sB[nxt][lob]);
      if (BN == 128) async_copy16(pb0 + 16 * K + k0 + 32, &sB[nxt][lob + 512]);
    }

    bf16x8 af[4], bw[JT];
#pragma unroll
    for (int i = 0; i < 4; ++i)
      af[i] = *(const bf16x8*)(&sA[cur][(wm + i * 16 + l16) * 32 + quad * 8]);
#pragma unroll
    for (int j = 0; j < JT; ++j)
      bw[j] = *(const bf16x8*)(&sB[cur][(wn + j * 16 + l16) * 32 + quad * 8]);
#pragma unroll
    for (int i = 0; i < 4; ++i)
#pragma unroll
      for (int j = 0; j < JT; ++j)
        acc[i][j] = MFMA_BF16(af[i], bw[j], acc[i][j]);
  }

  float bi[JT];
#pragma unroll
  for (int j = 0; j < JT; ++j) bi[j] = bias[n0 + wn + j * 16 + l16];

#pragma unroll
  for (int i = 0; i < 4; ++i) {
#pragma unroll
    for (int j = 0; j < JT; ++j) {
#pragma unroll
      for (int r = 0; r < 4; ++r) {
        size_t row = m0 + wm + i * 16 + quad * 4 + r;
        size_t col = n0 + wn + j * 16 + l16;
        float v = acc[i][j][r] + bi[j];
        if (out_bf16) ((__bf16*)C)[row * ldc + col] = (__bf16)v;
        else          ((float*)C)[row * ldc + col] = v;
      }
    }
  }
}

// ---------------- V transpose: qkv v-slice (n, d) -> vt[(b,h,dk)][l] ----------
__global__ __launch_bounds__(256) void vtrans_kernel(
    const __bf16* __restrict__ qkv, __bf16* __restrict__ vt)
{
  __shared__ __bf16 t[64][66];
  const int tid = threadIdx.x;
  const int bh = blockIdx.x;           // b*16+h
  const int b = bh >> 4, h = bh & 15;
  const int l0 = blockIdx.y * 64;
  const int r4 = tid >> 6;             // 0..3
  const int c  = tid & 63;
#pragma unroll
  for (int rep = 0; rep < 16; ++rep) {
    int ll = rep * 4 + r4;
    t[ll][c] = qkv[(size_t)(b * SEQ + l0 + ll) * LDQKV + 2048 + h * DKH + c];
  }
  __syncthreads();
#pragma unroll
  for (int rep = 0; rep < 16; ++rep) {
    int dk = rep * 4 + r4;
    vt[(size_t)(bh * DKH + dk) * SEQ + l0 + c] = t[c][dk];
  }
}

// ---------------- MFMA flash attention (causal) -------------------------------
// r3's exact verified kernel (42.8us measured): 4 waves x 16 queries,
// K/V^T 64x64 tiles double-buffered, balanced-qb swizzle, setprio on MFMA.
__global__ __launch_bounds__(256) void attn_kernel(
    const __bf16* __restrict__ qkv,   // [4096][3072]
    const __bf16* __restrict__ vt,    // [32*64][2048]
    __bf16* __restrict__ attn)        // [4096][1024]
{
  __shared__ __bf16 sK[2][64 * 64];   // [key][dk], granule-swizzled
  __shared__ __bf16 sV[2][64 * 64];   // [dk][key], granule-swizzled
  __shared__ __bf16 pbuf[4][16 * 64]; // per-wave P, [q][k] XOR-granule swizzle
  const int tid  = threadIdx.x;
  const int wave = tid >> 6, lane = tid & 63;
  const int quad = lane >> 4, l16 = lane & 15;
  const int id = blockIdx.x;
  const int u = (id >> 3) & 31, v = id & 7, w = id >> 8;
  const int bh = v * 4 + w;
  const int ue = u ^ ((w >> 1) << 3);         // temporal mix across the CU's 4 blocks
  const int qb = (w & 1) ? ue : 31 - ue;
  const int b = bh >> 4, h = bh & 15;
  const int q0 = qb * 64;
  const int qw = q0 + wave * 16;              // wave's first query row
  const size_t tokbase = (size_t)b * SEQ;

  // staging: lane l -> (row = l>>3, swizzled granule (l&7)^(l>>3))
  const int srow = lane >> 3;
  const int sgr  = (lane & 7) ^ srow;
  const __bf16* pKsrc = qkv + (tokbase + wave * 16 + srow) * LDQKV + 1024 + h * DKH + sgr * 8;
  const __bf16* pVsrc = vt + ((size_t)bh * DKH + wave * 16 + srow) * SEQ + sgr * 8;
  const int lo = wave * 16 * 64;              // wave's slab within buffer

  bf16x8 qf[2];
#pragma unroll
  for (int s = 0; s < 2; ++s)
    qf[s] = *(const bf16x8*)(qkv + (tokbase + qw + l16) * LDQKV + h * DKH + s * 32 + quad * 8);

  bf16x8 ones;
#pragma unroll
  for (int i = 0; i < 8; ++i) ones[i] = (__bf16)1.0f;

  f32x4 o[4], lacc;
  const f32x4 z = {0.f, 0.f, 0.f, 0.f};
#pragma unroll
  for (int t = 0; t < 4; ++t) o[t] = z;
  lacc = z;

  __bf16* pb = &pbuf[wave][0];
  const int swl = l16 & 7;   // K/V read-side swizzle key

  // prologue: stage key-tile 0 into buffer 0
  async_copy16(pKsrc, &sK[0][lo]);
  async_copy16(pKsrc + (size_t)8 * LDQKV, &sK[0][lo + 8 * 64]);
  async_copy16(pVsrc, &sV[0][lo]);
  async_copy16(pVsrc + (size_t)8 * SEQ, &sV[0][lo + 8 * 64]);

  for (int t0 = 0; t0 <= qb; ++t0) {
    const int cur = t0 & 1, nxt = cur ^ 1;
    __syncthreads();                 // tile t0 staged; prev reads of nxt done
    if (t0 < qb) {
      const size_t koff = (size_t)(t0 + 1) * 64;
      async_copy16(pKsrc + koff * LDQKV, &sK[nxt][lo]);
      async_copy16(pKsrc + (koff + 8) * LDQKV, &sK[nxt][lo + 8 * 64]);
      async_copy16(pVsrc + koff, &sV[nxt][lo]);
      async_copy16(pVsrc + (size_t)8 * SEQ + koff, &sV[nxt][lo + 8 * 64]);
    }
    const __bf16* K_ = &sK[cur][0];
    const __bf16* V_ = &sV[cur][0];

    // S^T = K Q^T : 4 row-tiles of 16 keys; lane holds keys ct*16+quad*4+r
    // for query l16 (C-layout with A=K, B=Q).
    f32x4 sacc[4];
    __builtin_amdgcn_s_setprio(1);
#pragma unroll
    for (int ct = 0; ct < 4; ++ct) {
      bf16x8 k0 = *(const bf16x8*)(K_ + (ct * 16 + l16) * 64 + ((quad ^ swl) * 8));
      bf16x8 k1 = *(const bf16x8*)(K_ + (ct * 16 + l16) * 64 + (((4 + quad) ^ swl) * 8));
      sacc[ct] = MFMA_BF16(k0, qf[0], z);
      sacc[ct] = MFMA_BF16(k1, qf[1], sacc[ct]);
    }
    __builtin_amdgcn_s_setprio(0);

    // P = exp2(S^T) -> packed bf16x4 -> per-wave LDS [q][k], XOR-swizzled
#pragma unroll
    for (int ct = 0; ct < 4; ++ct) {
      bf16x4 p4;
      if (t0 < qb) {
#pragma unroll
        for (int r = 0; r < 4; ++r) p4[r] = (__bf16)fast_exp2(sacc[ct][r]);
      } else {
#pragma unroll
        for (int r = 0; r < 4; ++r) {
          float sv = (ct * 16 + quad * 4 + r <= wave * 16 + l16) ? sacc[ct][r] : -1e30f;
          p4[r] = (__bf16)fast_exp2(sv);
        }
      }
      *(bf16x4*)(pb + l16 * 64 + (((ct * 4 + quad) ^ (swl << 1)) * 4)) = p4;
    }
    // A-layout fragments: 16B granule-pair t = quad+4h, swizzled by q&7
    bf16x8 ap0 = *(const bf16x8*)(pb + l16 * 64 + ((quad ^ swl) * 8));
    bf16x8 ap1 = *(const bf16x8*)(pb + l16 * 64 + (((4 + quad) ^ swl) * 8));

    __builtin_amdgcn_s_setprio(1);
    // l += P * 1 (row sums in C-layout: row quad*4+r = query — no shuffles)
    lacc = MFMA_BF16(ap0, ones, lacc);
    lacc = MFMA_BF16(ap1, ones, lacc);

    // O += P V : 4 dk-tiles
#pragma unroll
    for (int dt = 0; dt < 4; ++dt) {
      bf16x8 v0 = *(const bf16x8*)(V_ + (dt * 16 + l16) * 64 + ((quad ^ swl) * 8));
      bf16x8 v1 = *(const bf16x8*)(V_ + (dt * 16 + l16) * 64 + (((4 + quad) ^ swl) * 8));
      o[dt] = MFMA_BF16(ap0, v0, o[dt]);
      o[dt] = MFMA_BF16(ap1, v1, o[dt]);
    }
    __builtin_amdgcn_s_setprio(0);
  }

  float linv[4];
#pragma unroll
  for (int r = 0; r < 4; ++r) linv[r] = 1.0f / lacc[r];

#pragma unroll
  for (int dt = 0; dt < 4; ++dt)
#pragma unroll
    for (int r = 0; r < 4; ++r)
      attn[(tokbase + qw + quad * 4 + r) * DMODEL + h * DKH + dt * 16 + l16] =
          (__bf16)(o[dt][r] * linv[r]);
}

// ---------------- launch ------------------------------------------------------
extern "C" void kernel_launch(void* const* d_in, const int* in_sizes, int n_in,
                              void* d_out, int out_size, void* d_ws, size_t ws_size,
                              hipStream_t stream) {
  const float* x  = (const float*)d_in[0];
  const float* wq = (const float*)d_in[1];
  const float* bq = (const float*)d_in[2];
  const float* wk = (const float*)d_in[3];
  const float* bk = (const float*)d_in[4];
  const float* wv = (const float*)d_in[5];
  const float* bv = (const float*)d_in[6];
  const float* wo = (const float*)d_in[7];
  const float* bo = (const float*)d_in[8];

  char* ws = (char*)d_ws;
  __bf16* xb    = (__bf16*)(ws + 0);
  __bf16* wqkv  = (__bf16*)(ws + 8388608);
  __bf16* wob   = (__bf16*)(ws + 14680064);
  float*  bcat  = (float*)(ws + 16777216);
  __bf16* qkv   = (__bf16*)(ws + 16789504);
  __bf16* vt    = (__bf16*)(ws + 41955328);
  __bf16* attn  = (__bf16*)(ws + 50343936);
  float*  out   = (float*)d_out;

  pack_kernel<<<1024, 256, 0, stream>>>(
      (const float4*)x, (const float4*)wq, (const float4*)wk, (const float4*)wv,
      (const float4*)wo, (const float4*)bq, (const float4*)bk, (const float4*)bv,
      (bf16x4*)xb, (bf16x4*)wqkv, (bf16x4*)wob, (float4*)bcat);

  // fused QKV projection: M=4096, N=3072, K=1024, 256x192 phase-split kernel
  // (256 blocks = exactly 1/CU, XCD-chunked)
  gemm_qkv_256x192<<<256, 512, 0, stream>>>(xb, wqkv, bcat, qkv);

  vtrans_kernel<<<dim3(32, 32), 256, 0, stream>>>(qkv, vt);

  // flash attention: 1-D grid, balanced swizzle (r3 verified config)
  attn_kernel<<<1024, 256, 0, stream>>>(qkv, vt, attn);

  // output projection: M=4096, N=1024, K=1024, 128x64 tiles (512 blocks)
  gemm_bias<64><<<dim3(32, 16), 256, 0, stream>>>(attn, wob, bo, out, DMODEL, 0);
}

// Round 8
// 171.657 us; speedup vs baseline: 1.1010x; 1.0239x over previous
//
#include <hip/hip_runtime.h>
#include <cstdint>

// Problem constants: B=2, L=2048, D=1024, H=16, DK=64
#define SEQ     2048
#define DMODEL  1024
#define NHEAD   16
#define DKH     64
#define NTOK    4096      // B*L
#define LDQKV   3072      // qkv buffer row stride (q|k|v)

typedef __bf16 bf16x8 __attribute__((ext_vector_type(8)));
typedef __bf16 bf16x4 __attribute__((ext_vector_type(4)));
typedef float  f32x4  __attribute__((ext_vector_type(4)));

#define MFMA_BF16(a, b, c) __builtin_amdgcn_mfma_f32_16x16x32_bf16((a), (b), (c), 0, 0, 0)

// 0.125 * log2(e): folded into wq/bq at pack time. Softmax shift dropped
// entirely — exp2(s) scales O and l identically, cancels in O/l.
#define C2F 0.18033688f

__device__ inline float fast_exp2(float x) {
#if __has_builtin(__builtin_amdgcn_exp2f)
  return __builtin_amdgcn_exp2f(x);
#else
  return __expf(x * 0.69314718056f);
#endif
}

// async global->LDS copy, 16B per lane; LDS dest is wave-uniform base + lane*16
__device__ inline void async_copy16(const void* g, void* l) {
  __builtin_amdgcn_global_load_lds(
      reinterpret_cast<const __attribute__((address_space(1))) void*>(
          reinterpret_cast<uintptr_t>(g)),
      reinterpret_cast<__attribute__((address_space(3))) void*>(
          reinterpret_cast<uintptr_t>(l)),
      16, 0, 0);
}

__device__ inline bf16x4 cvt4(float4 v) {
  bf16x4 r;
  r[0] = (__bf16)v.x; r[1] = (__bf16)v.y; r[2] = (__bf16)v.z; r[3] = (__bf16)v.w;
  return r;
}

// ---------------- pack: fp32 -> bf16 casts + weight/bias concat ----------------
__global__ __launch_bounds__(256) void pack_kernel(
    const float4* __restrict__ x,
    const float4* __restrict__ wq, const float4* __restrict__ wk,
    const float4* __restrict__ wv, const float4* __restrict__ wo,
    const float4* __restrict__ bq, const float4* __restrict__ bk,
    const float4* __restrict__ bv,
    bf16x4* __restrict__ xb, bf16x4* __restrict__ wqkv,
    bf16x4* __restrict__ wob, float4* __restrict__ bcat)
{
  const int NX = NTOK * DMODEL / 4;       // 1048576 float4 groups of x
  const int NW = DMODEL * DMODEL / 4;     // 262144 per weight
  const int TOT = NX + 4 * NW + 3 * (DMODEL / 4);
  for (int g = blockIdx.x * 256 + threadIdx.x; g < TOT; g += gridDim.x * 256) {
    if (g < NX) {
      xb[g] = cvt4(x[g]);
    } else if (g < NX + 3 * NW) {
      int g2 = g - NX;
      const float4* s = (g2 < NW) ? wq : (g2 < 2 * NW ? wk : wv);
      float4 v = s[g2 & (NW - 1)];
      if (g2 < NW) { v.x *= C2F; v.y *= C2F; v.z *= C2F; v.w *= C2F; }
      wqkv[g2] = cvt4(v);
    } else if (g < NX + 4 * NW) {
      int g3 = g - NX - 3 * NW;
      wob[g3] = cvt4(wo[g3]);
    } else {
      int g4 = g - NX - 4 * NW;
      const float4* s = (g4 < 256) ? bq : (g4 < 512 ? bk : bv);
      float4 v = s[g4 & 255];
      if (g4 < 256) { v.x *= C2F; v.y *= C2F; v.z *= C2F; v.w *= C2F; }
      bcat[g4] = v;
    }
  }
}

// ---------------- QKV GEMM, 256x192 tile, BK=64, 8 waves, phase-split ---------
// (r7 verified: 256 blocks = exactly 1/CU, XCD-chunked; contributed the r7
// win. Frozen.)
__global__ __launch_bounds__(512, 2) void gemm_qkv_256x192(
    const __bf16* __restrict__ A,    // xb  [4096][1024]
    const __bf16* __restrict__ W,    // wqkv [3072][1024]
    const float* __restrict__ bias,  // bcat [3072]
    __bf16* __restrict__ C)          // qkv [4096][3072]
{
  constexpr int K = 1024;
  __shared__ __bf16 sA[2][256 * 64];  // 32KB each
  __shared__ __bf16 sB[2][192 * 64];  // 24KB each
  const int tid  = threadIdx.x;
  const int wave = tid >> 6, lane = tid & 63;
  const int quad = lane >> 4, l16 = lane & 15;
  const int wm = wave >> 2, wn = wave & 3;     // 2 x 4 wave grid
  const int swl = l16 & 7;
  const int bid = blockIdx.x;
  const int xcd = bid & 7, slot = bid >> 3;
  const int mt = (xcd >> 1) * 4 + (slot >> 3);   // 0..15
  const int nt = (xcd & 1) * 8 + (slot & 7);     // 0..15
  const size_t m0 = (size_t)mt * 256;
  const size_t n0 = (size_t)nt * 192;

  // staging bases: lane -> (row = chunk*8 + lane>>3, LDS granule lane&7,
  // source granule pre-swizzled by row&7)
  const int srow = lane >> 3;
  const int sgr  = (lane & 7) ^ srow;
  const __bf16* pA = A + (m0 + srow) * K + sgr * 8;
  const __bf16* pB = W + (n0 + srow) * K + sgr * 8;

  f32x4 acc[8][3];
  const f32x4 z = {0.f, 0.f, 0.f, 0.f};
#pragma unroll
  for (int i = 0; i < 8; ++i)
#pragma unroll
    for (int j = 0; j < 3; ++j) acc[i][j] = z;

#define STAGE_QKV(buf, k0)                                                    \
  {                                                                           \
    _Pragma("unroll")                                                         \
    for (int L = 0; L < 4; ++L) {          /* A: 32 chunks of 8 rows */       \
      const int c = L * 8 + wave;                                             \
      async_copy16(pA + (size_t)(c * 8) * K + (k0), &sA[buf][c * 512]);       \
    }                                                                         \
    _Pragma("unroll")                                                         \
    for (int L = 0; L < 3; ++L) {          /* B: 24 chunks of 8 rows */       \
      const int c = L * 8 + wave;                                             \
      async_copy16(pB + (size_t)(c * 8) * K + (k0), &sB[buf][c * 512]);       \
    }                                                                         \
  }

  int cur = 0;
  STAGE_QKV(0, 0);
  __syncthreads();                   // vmcnt(0) drain: tile 0 landed

  for (int t = 0; t < 16; ++t) {
    const __bf16* A_ = &sA[cur][0];
    const __bf16* B_ = &sB[cur][0];
    if (t + 1 < 16) STAGE_QKV(cur ^ 1, (t + 1) * 64);   // earliest issue

    bf16x8 af[4][2], bw[3][2];
    // ---- phase 1: B cols (all 3 j) + A rows 0..63 of wave; acc[0..3][*]
#pragma unroll
    for (int j = 0; j < 3; ++j) {
      const __bf16* r = B_ + (wn * 48 + j * 16 + l16) * 64;
      bw[j][0] = *(const bf16x8*)(r + ((quad ^ swl) * 8));
      bw[j][1] = *(const bf16x8*)(r + (((4 + quad) ^ swl) * 8));
    }
#pragma unroll
    for (int i = 0; i < 4; ++i) {
      const __bf16* r = A_ + (wm * 128 + i * 16 + l16) * 64;
      af[i][0] = *(const bf16x8*)(r + ((quad ^ swl) * 8));
      af[i][1] = *(const bf16x8*)(r + (((4 + quad) ^ swl) * 8));
    }
    __builtin_amdgcn_s_setprio(1);
#pragma unroll
    for (int i = 0; i < 4; ++i)
#pragma unroll
      for (int j = 0; j < 3; ++j) {
        acc[i][j] = MFMA_BF16(af[i][0], bw[j][0], acc[i][j]);
        acc[i][j] = MFMA_BF16(af[i][1], bw[j][1], acc[i][j]);
      }
    __builtin_amdgcn_s_setprio(0);
    __builtin_amdgcn_s_barrier();

    // ---- phase 2: A rows 64..127 (overwrite af); acc[4..7][*]; boundary
#pragma unroll
    for (int i = 0; i < 4; ++i) {
      const __bf16* r = A_ + (wm * 128 + 64 + i * 16 + l16) * 64;
      af[i][0] = *(const bf16x8*)(r + ((quad ^ swl) * 8));
      af[i][1] = *(const bf16x8*)(r + (((4 + quad) ^ swl) * 8));
    }
    __builtin_amdgcn_s_setprio(1);
#pragma unroll
    for (int i = 0; i < 4; ++i)
#pragma unroll
      for (int j = 0; j < 3; ++j) {
        acc[4 + i][j] = MFMA_BF16(af[i][0], bw[j][0], acc[4 + i][j]);
        acc[4 + i][j] = MFMA_BF16(af[i][1], bw[j][1], acc[4 + i][j]);
      }
    __builtin_amdgcn_s_setprio(0);
    asm volatile("s_waitcnt vmcnt(0)" ::: "memory");  // next tile landed
    __builtin_amdgcn_s_barrier();
    cur ^= 1;
  }
#undef STAGE_QKV

  float bi[3];
#pragma unroll
  for (int j = 0; j < 3; ++j) bi[j] = bias[n0 + wn * 48 + j * 16 + l16];

#pragma unroll
  for (int i = 0; i < 8; ++i)
#pragma unroll
    for (int j = 0; j < 3; ++j)
#pragma unroll
      for (int r = 0; r < 4; ++r) {
        size_t row = m0 + wm * 128 + i * 16 + quad * 4 + r;
        size_t col = n0 + wn * 48 + j * 16 + l16;
        C[row * LDQKV + col] = (__bf16)(acc[i][j][r] + bi[j]);
      }
}

// ---------------- out-proj GEMM, 128x128 tile, BK=64, 8 waves -----------------
// C[4096,1024] f32 = A[4096,1024] * W[1024,1024]^T + bias.
// r8: same template as the r7-verified QKV kernel at out-proj geometry:
// 32x8 = 256 blocks = exactly 1/CU. Per wave (2Mx4N): 64x32 of C, acc[4][2],
// 16 MFMA/K-tile; single phase per tile (stage-early at top, one boundary
// vmcnt(0)+s_barrier). Stage 32KB/tile (~570cyc L2) vs 128 MFMA (~600cyc) —
// balanced. LDS 64KB (2 buffers). Same stage/read swizzle idioms (row&7 ==
// l16&7: 64/32/16 all = 0 mod 8). XCD map: xcd = bid&7 owns mt-range of 4
// (A-panel 1MB) x all nt (W 2MB) ~ 3MB < its 4MB L2. Bijective.
__global__ __launch_bounds__(512, 2) void gemm_out_128(
    const __bf16* __restrict__ A,    // attn [4096][1024]
    const __bf16* __restrict__ W,    // wob  [1024][1024]
    const float* __restrict__ bias,  // bo   [1024]
    float* __restrict__ C)           // out  [4096][1024]
{
  constexpr int K = 1024;
  __shared__ __bf16 sA[2][128 * 64];  // 16KB each
  __shared__ __bf16 sB[2][128 * 64];
  const int tid  = threadIdx.x;
  const int wave = tid >> 6, lane = tid & 63;
  const int quad = lane >> 4, l16 = lane & 15;
  const int wm = wave >> 2, wn = wave & 3;     // 2 x 4 wave grid
  const int swl = l16 & 7;
  const int bid = blockIdx.x;
  const int xcd = bid & 7, slot = bid >> 3;    // slot 0..31
  const int mt = xcd * 4 + (slot >> 3);        // 0..31
  const int nt = slot & 7;                     // 0..7
  const size_t m0 = (size_t)mt * 128;
  const size_t n0 = (size_t)nt * 128;

  const int srow = lane >> 3;
  const int sgr  = (lane & 7) ^ srow;
  const __bf16* pA = A + (m0 + srow) * K + sgr * 8;
  const __bf16* pB = W + (n0 + srow) * K + sgr * 8;

  f32x4 acc[4][2];
  const f32x4 z = {0.f, 0.f, 0.f, 0.f};
#pragma unroll
  for (int i = 0; i < 4; ++i)
#pragma unroll
    for (int j = 0; j < 2; ++j) acc[i][j] = z;

#define STAGE_OUT(buf, k0)                                                    \
  {                                                                           \
    _Pragma("unroll")                                                         \
    for (int L = 0; L < 2; ++L) {          /* 16 chunks of 8 rows each */     \
      const int c = L * 8 + wave;                                             \
      async_copy16(pA + (size_t)(c * 8) * K + (k0), &sA[buf][c * 512]);       \
      async_copy16(pB + (size_t)(c * 8) * K + (k0), &sB[buf][c * 512]);       \
    }                                                                         \
  }

  int cur = 0;
  STAGE_OUT(0, 0);
  __syncthreads();                   // vmcnt(0) drain: tile 0 landed

  for (int t = 0; t < 16; ++t) {
    const __bf16* A_ = &sA[cur][0];
    const __bf16* B_ = &sB[cur][0];
    if (t + 1 < 16) STAGE_OUT(cur ^ 1, (t + 1) * 64);   // earliest issue

    bf16x8 af[4][2], bw[2][2];
#pragma unroll
    for (int j = 0; j < 2; ++j) {
      const __bf16* r = B_ + (wn * 32 + j * 16 + l16) * 64;
      bw[j][0] = *(const bf16x8*)(r + ((quad ^ swl) * 8));
      bw[j][1] = *(const bf16x8*)(r + (((4 + quad) ^ swl) * 8));
    }
#pragma unroll
    for (int i = 0; i < 4; ++i) {
      const __bf16* r = A_ + (wm * 64 + i * 16 + l16) * 64;
      af[i][0] = *(const bf16x8*)(r + ((quad ^ swl) * 8));
      af[i][1] = *(const bf16x8*)(r + (((4 + quad) ^ swl) * 8));
    }
    __builtin_amdgcn_s_setprio(1);
#pragma unroll
    for (int i = 0; i < 4; ++i)
#pragma unroll
      for (int j = 0; j < 2; ++j) {
        acc[i][j] = MFMA_BF16(af[i][0], bw[j][0], acc[i][j]);
        acc[i][j] = MFMA_BF16(af[i][1], bw[j][1], acc[i][j]);
      }
    __builtin_amdgcn_s_setprio(0);
    asm volatile("s_waitcnt vmcnt(0)" ::: "memory");  // next tile landed
    __builtin_amdgcn_s_barrier();    // all reads of cur done; nxt complete
    cur ^= 1;
  }
#undef STAGE_OUT

  float bi[2];
#pragma unroll
  for (int j = 0; j < 2; ++j) bi[j] = bias[n0 + wn * 32 + j * 16 + l16];

#pragma unroll
  for (int i = 0; i < 4; ++i)
#pragma unroll
    for (int j = 0; j < 2; ++j)
#pragma unroll
      for (int r = 0; r < 4; ++r) {
        size_t row = m0 + wm * 64 + i * 16 + quad * 4 + r;
        size_t col = n0 + wn * 32 + j * 16 + l16;
        C[row * DMODEL + col] = acc[i][j][r] + bi[j];
      }
}

// ---------------- V transpose: qkv v-slice (n, d) -> vt[(b,h,dk)][l] ----------
__global__ __launch_bounds__(256) void vtrans_kernel(
    const __bf16* __restrict__ qkv, __bf16* __restrict__ vt)
{
  __shared__ __bf16 t[64][66];
  const int tid = threadIdx.x;
  const int bh = blockIdx.x;           // b*16+h
  const int b = bh >> 4, h = bh & 15;
  const int l0 = blockIdx.y * 64;
  const int r4 = tid >> 6;             // 0..3
  const int c  = tid & 63;
#pragma unroll
  for (int rep = 0; rep < 16; ++rep) {
    int ll = rep * 4 + r4;
    t[ll][c] = qkv[(size_t)(b * SEQ + l0 + ll) * LDQKV + 2048 + h * DKH + c];
  }
  __syncthreads();
#pragma unroll
  for (int rep = 0; rep < 16; ++rep) {
    int dk = rep * 4 + r4;
    vt[(size_t)(bh * DKH + dk) * SEQ + l0 + c] = t[c][dk];
  }
}

// ---------------- MFMA flash attention (causal) -------------------------------
// r3's exact verified kernel (42.8us measured): 4 waves x 16 queries,
// K/V^T 64x64 tiles double-buffered, balanced-qb swizzle, setprio on MFMA.
__global__ __launch_bounds__(256) void attn_kernel(
    const __bf16* __restrict__ qkv,   // [4096][3072]
    const __bf16* __restrict__ vt,    // [32*64][2048]
    __bf16* __restrict__ attn)        // [4096][1024]
{
  __shared__ __bf16 sK[2][64 * 64];   // [key][dk], granule-swizzled
  __shared__ __bf16 sV[2][64 * 64];   // [dk][key], granule-swizzled
  __shared__ __bf16 pbuf[4][16 * 64]; // per-wave P, [q][k] XOR-granule swizzle
  const int tid  = threadIdx.x;
  const int wave = tid >> 6, lane = tid & 63;
  const int quad = lane >> 4, l16 = lane & 15;
  const int id = blockIdx.x;
  const int u = (id >> 3) & 31, v = id & 7, w = id >> 8;
  const int bh = v * 4 + w;
  const int ue = u ^ ((w >> 1) << 3);         // temporal mix across the CU's 4 blocks
  const int qb = (w & 1) ? ue : 31 - ue;
  const int b = bh >> 4, h = bh & 15;
  const int q0 = qb * 64;
  const int qw = q0 + wave * 16;              // wave's first query row
  const size_t tokbase = (size_t)b * SEQ;

  // staging: lane l -> (row = l>>3, swizzled granule (l&7)^(l>>3))
  const int srow = lane >> 3;
  const int sgr  = (lane & 7) ^ srow;
  const __bf16* pKsrc = qkv + (tokbase + wave * 16 + srow) * LDQKV + 1024 + h * DKH + sgr * 8;
  const __bf16* pVsrc = vt + ((size_t)bh * DKH + wave * 16 + srow) * SEQ + sgr * 8;
  const int lo = wave * 16 * 64;              // wave's slab within buffer

  bf16x8 qf[2];
#pragma unroll
  for (int s = 0; s < 2; ++s)
    qf[s] = *(const bf16x8*)(qkv + (tokbase + qw + l16) * LDQKV + h * DKH + s * 32 + quad * 8);

  bf16x8 ones;
#pragma unroll
  for (int i = 0; i < 8; ++i) ones[i] = (__bf16)1.0f;

  f32x4 o[4], lacc;
  const f32x4 z = {0.f, 0.f, 0.f, 0.f};
#pragma unroll
  for (int t = 0; t < 4; ++t) o[t] = z;
  lacc = z;

  __bf16* pb = &pbuf[wave][0];
  const int swl = l16 & 7;   // K/V read-side swizzle key

  // prologue: stage key-tile 0 into buffer 0
  async_copy16(pKsrc, &sK[0][lo]);
  async_copy16(pKsrc + (size_t)8 * LDQKV, &sK[0][lo + 8 * 64]);
  async_copy16(pVsrc, &sV[0][lo]);
  async_copy16(pVsrc + (size_t)8 * SEQ, &sV[0][lo + 8 * 64]);

  for (int t0 = 0; t0 <= qb; ++t0) {
    const int cur = t0 & 1, nxt = cur ^ 1;
    __syncthreads();                 // tile t0 staged; prev reads of nxt done
    if (t0 < qb) {
      const size_t koff = (size_t)(t0 + 1) * 64;
      async_copy16(pKsrc + koff * LDQKV, &sK[nxt][lo]);
      async_copy16(pKsrc + (koff + 8) * LDQKV, &sK[nxt][lo + 8 * 64]);
      async_copy16(pVsrc + koff, &sV[nxt][lo]);
      async_copy16(pVsrc + (size_t)8 * SEQ + koff, &sV[nxt][lo + 8 * 64]);
    }
    const __bf16* K_ = &sK[cur][0];
    const __bf16* V_ = &sV[cur][0];

    // S^T = K Q^T : 4 row-tiles of 16 keys; lane holds keys ct*16+quad*4+r
    // for query l16 (C-layout with A=K, B=Q).
    f32x4 sacc[4];
    __builtin_amdgcn_s_setprio(1);
#pragma unroll
    for (int ct = 0; ct < 4; ++ct) {
      bf16x8 k0 = *(const bf16x8*)(K_ + (ct * 16 + l16) * 64 + ((quad ^ swl) * 8));
      bf16x8 k1 = *(const bf16x8*)(K_ + (ct * 16 + l16) * 64 + (((4 + quad) ^ swl) * 8));
      sacc[ct] = MFMA_BF16(k0, qf[0], z);
      sacc[ct] = MFMA_BF16(k1, qf[1], sacc[ct]);
    }
    __builtin_amdgcn_s_setprio(0);

    // P = exp2(S^T) -> packed bf16x4 -> per-wave LDS [q][k], XOR-swizzled
#pragma unroll
    for (int ct = 0; ct < 4; ++ct) {
      bf16x4 p4;
      if (t0 < qb) {
#pragma unroll
        for (int r = 0; r < 4; ++r) p4[r] = (__bf16)fast_exp2(sacc[ct][r]);
      } else {
#pragma unroll
        for (int r = 0; r < 4; ++r) {
          float sv = (ct * 16 + quad * 4 + r <= wave * 16 + l16) ? sacc[ct][r] : -1e30f;
          p4[r] = (__bf16)fast_exp2(sv);
        }
      }
      *(bf16x4*)(pb + l16 * 64 + (((ct * 4 + quad) ^ (swl << 1)) * 4)) = p4;
    }
    // A-layout fragments: 16B granule-pair t = quad+4h, swizzled by q&7
    bf16x8 ap0 = *(const bf16x8*)(pb + l16 * 64 + ((quad ^ swl) * 8));
    bf16x8 ap1 = *(const bf16x8*)(pb + l16 * 64 + (((4 + quad) ^ swl) * 8));

    __builtin_amdgcn_s_setprio(1);
    // l += P * 1 (row sums in C-layout: row quad*4+r = query — no shuffles)
    lacc = MFMA_BF16(ap0, ones, lacc);
    lacc = MFMA_BF16(ap1, ones, lacc);

    // O += P V : 4 dk-tiles
#pragma unroll
    for (int dt = 0; dt < 4; ++dt) {
      bf16x8 v0 = *(const bf16x8*)(V_ + (dt * 16 + l16) * 64 + ((quad ^ swl) * 8));
      bf16x8 v1 = *(const bf16x8*)(V_ + (dt * 16 + l16) * 64 + (((4 + quad) ^ swl) * 8));
      o[dt] = MFMA_BF16(ap0, v0, o[dt]);
      o[dt] = MFMA_BF16(ap1, v1, o[dt]);
    }
    __builtin_amdgcn_s_setprio(0);
  }

  float linv[4];
#pragma unroll
  for (int r = 0; r < 4; ++r) linv[r] = 1.0f / lacc[r];

#pragma unroll
  for (int dt = 0; dt < 4; ++dt)
#pragma unroll
    for (int r = 0; r < 4; ++r)
      attn[(tokbase + qw + quad * 4 + r) * DMODEL + h * DKH + dt * 16 + l16] =
          (__bf16)(o[dt][r] * linv[r]);
}

// ---------------- launch ------------------------------------------------------
extern "C" void kernel_launch(void* const* d_in, const int* in_sizes, int n_in,
                              void* d_out, int out_size, void* d_ws, size_t ws_size,
                              hipStream_t stream) {
  const float* x  = (const float*)d_in[0];
  const float* wq = (const float*)d_in[1];
  const float* bq = (const float*)d_in[2];
  const float* wk = (const float*)d_in[3];
  const float* bk = (const float*)d_in[4];
  const float* wv = (const float*)d_in[5];
  const float* bv = (const float*)d_in[6];
  const float* wo = (const float*)d_in[7];
  const float* bo = (const float*)d_in[8];

  char* ws = (char*)d_ws;
  __bf16* xb    = (__bf16*)(ws + 0);
  __bf16* wqkv  = (__bf16*)(ws + 8388608);
  __bf16* wob   = (__bf16*)(ws + 14680064);
  float*  bcat  = (float*)(ws + 16777216);
  __bf16* qkv   = (__bf16*)(ws + 16789504);
  __bf16* vt    = (__bf16*)(ws + 41955328);
  __bf16* attn  = (__bf16*)(ws + 50343936);
  float*  out   = (float*)d_out;

  pack_kernel<<<1024, 256, 0, stream>>>(
      (const float4*)x, (const float4*)wq, (const float4*)wk, (const float4*)wv,
      (const float4*)wo, (const float4*)bq, (const float4*)bk, (const float4*)bv,
      (bf16x4*)xb, (bf16x4*)wqkv, (bf16x4*)wob, (float4*)bcat);

  // fused QKV projection: M=4096, N=3072, K=1024, 256x192 phase-split kernel
  // (256 blocks = exactly 1/CU, XCD-chunked)
  gemm_qkv_256x192<<<256, 512, 0, stream>>>(xb, wqkv, bcat, qkv);

  vtrans_kernel<<<dim3(32, 32), 256, 0, stream>>>(qkv, vt);

  // flash attention: 1-D grid, balanced swizzle (r3 verified config)
  attn_kernel<<<1024, 256, 0, stream>>>(qkv, vt, attn);

  // output projection: M=4096, N=1024, K=1024, 128x128 phase-split kernel
  // (256 blocks = exactly 1/CU, XCD-chunked)
  gemm_out_128<<<256, 512, 0, stream>>>(attn, wob, bo, out);
}

// Round 9
// 171.597 us; speedup vs baseline: 1.1014x; 1.0004x over previous
//
#include <hip/hip_runtime.h>
#include <cstdint>

// Problem constants: B=2, L=2048, D=1024, H=16, DK=64
#define SEQ     2048
#define DMODEL  1024
#define NHEAD   16
#define DKH     64
#define NTOK    4096      // B*L
#define LDQKV   3072      // qkv buffer row stride (q|k|v)

typedef __bf16 bf16x8 __attribute__((ext_vector_type(8)));
typedef __bf16 bf16x4 __attribute__((ext_vector_type(4)));
typedef float  f32x4  __attribute__((ext_vector_type(4)));

#define MFMA_BF16(a, b, c) __builtin_amdgcn_mfma_f32_16x16x32_bf16((a), (b), (c), 0, 0, 0)

// 0.125 * log2(e): folded into wq/bq at pack time. Softmax shift dropped
// entirely — exp2(s) scales O and l identically, cancels in O/l.
#define C2F 0.18033688f

__device__ inline float fast_exp2(float x) {
#if __has_builtin(__builtin_amdgcn_exp2f)
  return __builtin_amdgcn_exp2f(x);
#else
  return __expf(x * 0.69314718056f);
#endif
}

// async global->LDS copy, 16B per lane; LDS dest is wave-uniform base + lane*16
__device__ inline void async_copy16(const void* g, void* l) {
  __builtin_amdgcn_global_load_lds(
      reinterpret_cast<const __attribute__((address_space(1))) void*>(
          reinterpret_cast<uintptr_t>(g)),
      reinterpret_cast<__attribute__((address_space(3))) void*>(
          reinterpret_cast<uintptr_t>(l)),
      16, 0, 0);
}

__device__ inline bf16x4 cvt4(float4 v) {
  bf16x4 r;
  r[0] = (__bf16)v.x; r[1] = (__bf16)v.y; r[2] = (__bf16)v.z; r[3] = (__bf16)v.w;
  return r;
}

// ---------------- pack: fp32 -> bf16 casts + weight/bias concat ----------------
__global__ __launch_bounds__(256) void pack_kernel(
    const float4* __restrict__ x,
    const float4* __restrict__ wq, const float4* __restrict__ wk,
    const float4* __restrict__ wv, const float4* __restrict__ wo,
    const float4* __restrict__ bq, const float4* __restrict__ bk,
    const float4* __restrict__ bv,
    bf16x4* __restrict__ xb, bf16x4* __restrict__ wqkv,
    bf16x4* __restrict__ wob, float4* __restrict__ bcat)
{
  const int NX = NTOK * DMODEL / 4;       // 1048576 float4 groups of x
  const int NW = DMODEL * DMODEL / 4;     // 262144 per weight
  const int TOT = NX + 4 * NW + 3 * (DMODEL / 4);
  for (int g = blockIdx.x * 256 + threadIdx.x; g < TOT; g += gridDim.x * 256) {
    if (g < NX) {
      xb[g] = cvt4(x[g]);
    } else if (g < NX + 3 * NW) {
      int g2 = g - NX;
      const float4* s = (g2 < NW) ? wq : (g2 < 2 * NW ? wk : wv);
      float4 v = s[g2 & (NW - 1)];
      if (g2 < NW) { v.x *= C2F; v.y *= C2F; v.z *= C2F; v.w *= C2F; }
      wqkv[g2] = cvt4(v);
    } else if (g < NX + 4 * NW) {
      int g3 = g - NX - 3 * NW;
      wob[g3] = cvt4(wo[g3]);
    } else {
      int g4 = g - NX - 4 * NW;
      const float4* s = (g4 < 256) ? bq : (g4 < 512 ? bk : bv);
      float4 v = s[g4 & 255];
      if (g4 < 256) { v.x *= C2F; v.y *= C2F; v.z *= C2F; v.w *= C2F; }
      bcat[g4] = v;
    }
  }
}

// ---------------- QKV GEMM, 256x192 tile, BK=64, 8 waves, phase-split ---------
// (r7 verified: 256 blocks = exactly 1/CU, XCD-chunked. Frozen.)
__global__ __launch_bounds__(512, 2) void gemm_qkv_256x192(
    const __bf16* __restrict__ A,    // xb  [4096][1024]
    const __bf16* __restrict__ W,    // wqkv [3072][1024]
    const float* __restrict__ bias,  // bcat [3072]
    __bf16* __restrict__ C)          // qkv [4096][3072]
{
  constexpr int K = 1024;
  __shared__ __bf16 sA[2][256 * 64];  // 32KB each
  __shared__ __bf16 sB[2][192 * 64];  // 24KB each
  const int tid  = threadIdx.x;
  const int wave = tid >> 6, lane = tid & 63;
  const int quad = lane >> 4, l16 = lane & 15;
  const int wm = wave >> 2, wn = wave & 3;     // 2 x 4 wave grid
  const int swl = l16 & 7;
  const int bid = blockIdx.x;
  const int xcd = bid & 7, slot = bid >> 3;
  const int mt = (xcd >> 1) * 4 + (slot >> 3);   // 0..15
  const int nt = (xcd & 1) * 8 + (slot & 7);     // 0..15
  const size_t m0 = (size_t)mt * 256;
  const size_t n0 = (size_t)nt * 192;

  // staging bases: lane -> (row = chunk*8 + lane>>3, LDS granule lane&7,
  // source granule pre-swizzled by row&7)
  const int srow = lane >> 3;
  const int sgr  = (lane & 7) ^ srow;
  const __bf16* pA = A + (m0 + srow) * K + sgr * 8;
  const __bf16* pB = W + (n0 + srow) * K + sgr * 8;

  f32x4 acc[8][3];
  const f32x4 z = {0.f, 0.f, 0.f, 0.f};
#pragma unroll
  for (int i = 0; i < 8; ++i)
#pragma unroll
    for (int j = 0; j < 3; ++j) acc[i][j] = z;

#define STAGE_QKV(buf, k0)                                                    \
  {                                                                           \
    _Pragma("unroll")                                                         \
    for (int L = 0; L < 4; ++L) {          /* A: 32 chunks of 8 rows */       \
      const int c = L * 8 + wave;                                             \
      async_copy16(pA + (size_t)(c * 8) * K + (k0), &sA[buf][c * 512]);       \
    }                                                                         \
    _Pragma("unroll")                                                         \
    for (int L = 0; L < 3; ++L) {          /* B: 24 chunks of 8 rows */       \
      const int c = L * 8 + wave;                                             \
      async_copy16(pB + (size_t)(c * 8) * K + (k0), &sB[buf][c * 512]);       \
    }                                                                         \
  }

  int cur = 0;
  STAGE_QKV(0, 0);
  __syncthreads();                   // vmcnt(0) drain: tile 0 landed

  for (int t = 0; t < 16; ++t) {
    const __bf16* A_ = &sA[cur][0];
    const __bf16* B_ = &sB[cur][0];
    if (t + 1 < 16) STAGE_QKV(cur ^ 1, (t + 1) * 64);   // earliest issue

    bf16x8 af[4][2], bw[3][2];
    // ---- phase 1: B cols (all 3 j) + A rows 0..63 of wave; acc[0..3][*]
#pragma unroll
    for (int j = 0; j < 3; ++j) {
      const __bf16* r = B_ + (wn * 48 + j * 16 + l16) * 64;
      bw[j][0] = *(const bf16x8*)(r + ((quad ^ swl) * 8));
      bw[j][1] = *(const bf16x8*)(r + (((4 + quad) ^ swl) * 8));
    }
#pragma unroll
    for (int i = 0; i < 4; ++i) {
      const __bf16* r = A_ + (wm * 128 + i * 16 + l16) * 64;
      af[i][0] = *(const bf16x8*)(r + ((quad ^ swl) * 8));
      af[i][1] = *(const bf16x8*)(r + (((4 + quad) ^ swl) * 8));
    }
    __builtin_amdgcn_s_setprio(1);
#pragma unroll
    for (int i = 0; i < 4; ++i)
#pragma unroll
      for (int j = 0; j < 3; ++j) {
        acc[i][j] = MFMA_BF16(af[i][0], bw[j][0], acc[i][j]);
        acc[i][j] = MFMA_BF16(af[i][1], bw[j][1], acc[i][j]);
      }
    __builtin_amdgcn_s_setprio(0);
    __builtin_amdgcn_s_barrier();

    // ---- phase 2: A rows 64..127 (overwrite af); acc[4..7][*]; boundary
#pragma unroll
    for (int i = 0; i < 4; ++i) {
      const __bf16* r = A_ + (wm * 128 + 64 + i * 16 + l16) * 64;
      af[i][0] = *(const bf16x8*)(r + ((quad ^ swl) * 8));
      af[i][1] = *(const bf16x8*)(r + (((4 + quad) ^ swl) * 8));
    }
    __builtin_amdgcn_s_setprio(1);
#pragma unroll
    for (int i = 0; i < 4; ++i)
#pragma unroll
      for (int j = 0; j < 3; ++j) {
        acc[4 + i][j] = MFMA_BF16(af[i][0], bw[j][0], acc[4 + i][j]);
        acc[4 + i][j] = MFMA_BF16(af[i][1], bw[j][1], acc[4 + i][j]);
      }
    __builtin_amdgcn_s_setprio(0);
    asm volatile("s_waitcnt vmcnt(0)" ::: "memory");  // next tile landed
    __builtin_amdgcn_s_barrier();
    cur ^= 1;
  }
#undef STAGE_QKV

  float bi[3];
#pragma unroll
  for (int j = 0; j < 3; ++j) bi[j] = bias[n0 + wn * 48 + j * 16 + l16];

#pragma unroll
  for (int i = 0; i < 8; ++i)
#pragma unroll
    for (int j = 0; j < 3; ++j)
#pragma unroll
      for (int r = 0; r < 4; ++r) {
        size_t row = m0 + wm * 128 + i * 16 + quad * 4 + r;
        size_t col = n0 + wn * 48 + j * 16 + l16;
        C[row * LDQKV + col] = (__bf16)(acc[i][j][r] + bi[j]);
      }
}

// ---------------- out-proj GEMM, 128x128 tile, BK=64, 8 waves -----------------
// (r8 verified: 256 blocks = exactly 1/CU, XCD-chunked. Frozen.)
__global__ __launch_bounds__(512, 2) void gemm_out_128(
    const __bf16* __restrict__ A,    // attn [4096][1024]
    const __bf16* __restrict__ W,    // wob  [1024][1024]
    const float* __restrict__ bias,  // bo   [1024]
    float* __restrict__ C)           // out  [4096][1024]
{
  constexpr int K = 1024;
  __shared__ __bf16 sA[2][128 * 64];  // 16KB each
  __shared__ __bf16 sB[2][128 * 64];
  const int tid  = threadIdx.x;
  const int wave = tid >> 6, lane = tid & 63;
  const int quad = lane >> 4, l16 = lane & 15;
  const int wm = wave >> 2, wn = wave & 3;     // 2 x 4 wave grid
  const int swl = l16 & 7;
  const int bid = blockIdx.x;
  const int xcd = bid & 7, slot = bid >> 3;    // slot 0..31
  const int mt = xcd * 4 + (slot >> 3);        // 0..31
  const int nt = slot & 7;                     // 0..7
  const size_t m0 = (size_t)mt * 128;
  const size_t n0 = (size_t)nt * 128;

  const int srow = lane >> 3;
  const int sgr  = (lane & 7) ^ srow;
  const __bf16* pA = A + (m0 + srow) * K + sgr * 8;
  const __bf16* pB = W + (n0 + srow) * K + sgr * 8;

  f32x4 acc[4][2];
  const f32x4 z = {0.f, 0.f, 0.f, 0.f};
#pragma unroll
  for (int i = 0; i < 4; ++i)
#pragma unroll
    for (int j = 0; j < 2; ++j) acc[i][j] = z;

#define STAGE_OUT(buf, k0)                                                    \
  {                                                                           \
    _Pragma("unroll")                                                         \
    for (int L = 0; L < 2; ++L) {          /* 16 chunks of 8 rows each */     \
      const int c = L * 8 + wave;                                             \
      async_copy16(pA + (size_t)(c * 8) * K + (k0), &sA[buf][c * 512]);       \
      async_copy16(pB + (size_t)(c * 8) * K + (k0), &sB[buf][c * 512]);       \
    }                                                                         \
  }

  int cur = 0;
  STAGE_OUT(0, 0);
  __syncthreads();                   // vmcnt(0) drain: tile 0 landed

  for (int t = 0; t < 16; ++t) {
    const __bf16* A_ = &sA[cur][0];
    const __bf16* B_ = &sB[cur][0];
    if (t + 1 < 16) STAGE_OUT(cur ^ 1, (t + 1) * 64);   // earliest issue

    bf16x8 af[4][2], bw[2][2];
#pragma unroll
    for (int j = 0; j < 2; ++j) {
      const __bf16* r = B_ + (wn * 32 + j * 16 + l16) * 64;
      bw[j][0] = *(const bf16x8*)(r + ((quad ^ swl) * 8));
      bw[j][1] = *(const bf16x8*)(r + (((4 + quad) ^ swl) * 8));
    }
#pragma unroll
    for (int i = 0; i < 4; ++i) {
      const __bf16* r = A_ + (wm * 64 + i * 16 + l16) * 64;
      af[i][0] = *(const bf16x8*)(r + ((quad ^ swl) * 8));
      af[i][1] = *(const bf16x8*)(r + (((4 + quad) ^ swl) * 8));
    }
    __builtin_amdgcn_s_setprio(1);
#pragma unroll
    for (int i = 0; i < 4; ++i)
#pragma unroll
      for (int j = 0; j < 2; ++j) {
        acc[i][j] = MFMA_BF16(af[i][0], bw[j][0], acc[i][j]);
        acc[i][j] = MFMA_BF16(af[i][1], bw[j][1], acc[i][j]);
      }
    __builtin_amdgcn_s_setprio(0);
    asm volatile("s_waitcnt vmcnt(0)" ::: "memory");  // next tile landed
    __builtin_amdgcn_s_barrier();    // all reads of cur done; nxt complete
    cur ^= 1;
  }
#undef STAGE_OUT

  float bi[2];
#pragma unroll
  for (int j = 0; j < 2; ++j) bi[j] = bias[n0 + wn * 32 + j * 16 + l16];

#pragma unroll
  for (int i = 0; i < 4; ++i)
#pragma unroll
    for (int j = 0; j < 2; ++j)
#pragma unroll
      for (int r = 0; r < 4; ++r) {
        size_t row = m0 + wm * 64 + i * 16 + quad * 4 + r;
        size_t col = n0 + wn * 32 + j * 16 + l16;
        C[row * DMODEL + col] = acc[i][j][r] + bi[j];
      }
}

// ---------------- V transpose: qkv v-slice (n, d) -> vt[(b,h,dk)][l] ----------
// r9: fully vectorized (old version was scalar 2B global loads/stores —
// Common-mistake #2). Both global sides bf16x8 (16B/lane, 128B per 8-lane
// row segment, coalesced). 64x64 LDS transpose tile with granule-XOR layout:
// chunk (row, gr) stored at granule gr ^ (row&7) ^ (row>>3) — keeps LDS
// writes 16B-aligned (no padding) and makes the column-gather reads
// conflict-free: for gather-instr k, row&7 = k (lane-uniform) while
// row>>3 = l&7 varies -> XOR spreads 8 lane-groups over 8 granule offsets
// (4 banks apart); dk&7 = l>>3 fills low bank bits. Bijective per row.
__global__ __launch_bounds__(256) void vtrans_kernel(
    const __bf16* __restrict__ qkv, __bf16* __restrict__ vt)
{
  __shared__ __bf16 t[64 * 64];        // 8KB
  const int tid = threadIdx.x;
  const int bh = blockIdx.x;           // b*16+h
  const int b = bh >> 4, h = bh & 15;
  const int l0 = blockIdx.y * 64;
  const size_t tokbase = (size_t)b * SEQ;

  // read: 512 chunks of 8 bf16; thread handles chunks tid and tid+256
#pragma unroll
  for (int p = 0; p < 2; ++p) {
    const int chunk = p * 256 + tid;
    const int row = chunk >> 3;        // token within tile
    const int gr  = chunk & 7;         // dk granule
    bf16x8 v = *(const bf16x8*)(
        qkv + (tokbase + l0 + row) * LDQKV + 2048 + h * DKH + gr * 8);
    const int g2 = gr ^ (row & 7) ^ (row >> 3);
    *(bf16x8*)(t + row * 64 + g2 * 8) = v;
  }
  __syncthreads();

  // write: 512 chunks; chunk -> (dk = chunk>>3, token group gc = chunk&7)
#pragma unroll
  for (int p = 0; p < 2; ++p) {
    const int chunk = p * 256 + tid;
    const int dk = chunk >> 3;
    const int gc = chunk & 7;
    bf16x8 o;
#pragma unroll
    for (int k = 0; k < 8; ++k) {
      const int row = gc * 8 + k;      // row&7 == k, row>>3 == gc
      const int g = (dk >> 3) ^ k ^ gc;
      o[k] = t[row * 64 + g * 8 + (dk & 7)];
    }
    *(bf16x8*)(vt + ((size_t)bh * DKH + dk) * SEQ + l0 + gc * 8) = o;
  }
}

// ---------------- MFMA flash attention (causal) -------------------------------
// r3's exact verified kernel (42.8us measured): 4 waves x 16 queries,
// K/V^T 64x64 tiles double-buffered, balanced-qb swizzle, setprio on MFMA.
__global__ __launch_bounds__(256) void attn_kernel(
    const __bf16* __restrict__ qkv,   // [4096][3072]
    const __bf16* __restrict__ vt,    // [32*64][2048]
    __bf16* __restrict__ attn)        // [4096][1024]
{
  __shared__ __bf16 sK[2][64 * 64];   // [key][dk], granule-swizzled
  __shared__ __bf16 sV[2][64 * 64];   // [dk][key], granule-swizzled
  __shared__ __bf16 pbuf[4][16 * 64]; // per-wave P, [q][k] XOR-granule swizzle
  const int tid  = threadIdx.x;
  const int wave = tid >> 6, lane = tid & 63;
  const int quad = lane >> 4, l16 = lane & 15;
  const int id = blockIdx.x;
  const int u = (id >> 3) & 31, v = id & 7, w = id >> 8;
  const int bh = v * 4 + w;
  const int ue = u ^ ((w >> 1) << 3);         // temporal mix across the CU's 4 blocks
  const int qb = (w & 1) ? ue : 31 - ue;
  const int b = bh >> 4, h = bh & 15;
  const int q0 = qb * 64;
  const int qw = q0 + wave * 16;              // wave's first query row
  const size_t tokbase = (size_t)b * SEQ;

  // staging: lane l -> (row = l>>3, swizzled granule (l&7)^(l>>3))
  const int srow = lane >> 3;
  const int sgr  = (lane & 7) ^ srow;
  const __bf16* pKsrc = qkv + (tokbase + wave * 16 + srow) * LDQKV + 1024 + h * DKH + sgr * 8;
  const __bf16* pVsrc = vt + ((size_t)bh * DKH + wave * 16 + srow) * SEQ + sgr * 8;
  const int lo = wave * 16 * 64;              // wave's slab within buffer

  bf16x8 qf[2];
#pragma unroll
  for (int s = 0; s < 2; ++s)
    qf[s] = *(const bf16x8*)(qkv + (tokbase + qw + l16) * LDQKV + h * DKH + s * 32 + quad * 8);

  bf16x8 ones;
#pragma unroll
  for (int i = 0; i < 8; ++i) ones[i] = (__bf16)1.0f;

  f32x4 o[4], lacc;
  const f32x4 z = {0.f, 0.f, 0.f, 0.f};
#pragma unroll
  for (int t = 0; t < 4; ++t) o[t] = z;
  lacc = z;

  __bf16* pb = &pbuf[wave][0];
  const int swl = l16 & 7;   // K/V read-side swizzle key

  // prologue: stage key-tile 0 into buffer 0
  async_copy16(pKsrc, &sK[0][lo]);
  async_copy16(pKsrc + (size_t)8 * LDQKV, &sK[0][lo + 8 * 64]);
  async_copy16(pVsrc, &sV[0][lo]);
  async_copy16(pVsrc + (size_t)8 * SEQ, &sV[0][lo + 8 * 64]);

  for (int t0 = 0; t0 <= qb; ++t0) {
    const int cur = t0 & 1, nxt = cur ^ 1;
    __syncthreads();                 // tile t0 staged; prev reads of nxt done
    if (t0 < qb) {
      const size_t koff = (size_t)(t0 + 1) * 64;
      async_copy16(pKsrc + koff * LDQKV, &sK[nxt][lo]);
      async_copy16(pKsrc + (koff + 8) * LDQKV, &sK[nxt][lo + 8 * 64]);
      async_copy16(pVsrc + koff, &sV[nxt][lo]);
      async_copy16(pVsrc + (size_t)8 * SEQ + koff, &sV[nxt][lo + 8 * 64]);
    }
    const __bf16* K_ = &sK[cur][0];
    const __bf16* V_ = &sV[cur][0];

    // S^T = K Q^T : 4 row-tiles of 16 keys; lane holds keys ct*16+quad*4+r
    // for query l16 (C-layout with A=K, B=Q).
    f32x4 sacc[4];
    __builtin_amdgcn_s_setprio(1);
#pragma unroll
    for (int ct = 0; ct < 4; ++ct) {
      bf16x8 k0 = *(const bf16x8*)(K_ + (ct * 16 + l16) * 64 + ((quad ^ swl) * 8));
      bf16x8 k1 = *(const bf16x8*)(K_ + (ct * 16 + l16) * 64 + (((4 + quad) ^ swl) * 8));
      sacc[ct] = MFMA_BF16(k0, qf[0], z);
      sacc[ct] = MFMA_BF16(k1, qf[1], sacc[ct]);
    }
    __builtin_amdgcn_s_setprio(0);

    // P = exp2(S^T) -> packed bf16x4 -> per-wave LDS [q][k], XOR-swizzled
#pragma unroll
    for (int ct = 0; ct < 4; ++ct) {
      bf16x4 p4;
      if (t0 < qb) {
#pragma unroll
        for (int r = 0; r < 4; ++r) p4[r] = (__bf16)fast_exp2(sacc[ct][r]);
      } else {
#pragma unroll
        for (int r = 0; r < 4; ++r) {
          float sv = (ct * 16 + quad * 4 + r <= wave * 16 + l16) ? sacc[ct][r] : -1e30f;
          p4[r] = (__bf16)fast_exp2(sv);
        }
      }
      *(bf16x4*)(pb + l16 * 64 + (((ct * 4 + quad) ^ (swl << 1)) * 4)) = p4;
    }
    // A-layout fragments: 16B granule-pair t = quad+4h, swizzled by q&7
    bf16x8 ap0 = *(const bf16x8*)(pb + l16 * 64 + ((quad ^ swl) * 8));
    bf16x8 ap1 = *(const bf16x8*)(pb + l16 * 64 + (((4 + quad) ^ swl) * 8));

    __builtin_amdgcn_s_setprio(1);
    // l += P * 1 (row sums in C-layout: row quad*4+r = query — no shuffles)
    lacc = MFMA_BF16(ap0, ones, lacc);
    lacc = MFMA_BF16(ap1, ones, lacc);

    // O += P V : 4 dk-tiles
#pragma unroll
    for (int dt = 0; dt < 4; ++dt) {
      bf16x8 v0 = *(const bf16x8*)(V_ + (dt * 16 + l16) * 64 + ((quad ^ swl) * 8));
      bf16x8 v1 = *(const bf16x8*)(V_ + (dt * 16 + l16) * 64 + (((4 + quad) ^ swl) * 8));
      o[dt] = MFMA_BF16(ap0, v0, o[dt]);
      o[dt] = MFMA_BF16(ap1, v1, o[dt]);
    }
    __builtin_amdgcn_s_setprio(0);
  }

  float linv[4];
#pragma unroll
  for (int r = 0; r < 4; ++r) linv[r] = 1.0f / lacc[r];

#pragma unroll
  for (int dt = 0; dt < 4; ++dt)
#pragma unroll
    for (int r = 0; r < 4; ++r)
      attn[(tokbase + qw + quad * 4 + r) * DMODEL + h * DKH + dt * 16 + l16] =
          (__bf16)(o[dt][r] * linv[r]);
}

// ---------------- launch ------------------------------------------------------
extern "C" void kernel_launch(void* const* d_in, const int* in_sizes, int n_in,
                              void* d_out, int out_size, void* d_ws, size_t ws_size,
                              hipStream_t stream) {
  const float* x  = (const float*)d_in[0];
  const float* wq = (const float*)d_in[1];
  const float* bq = (const float*)d_in[2];
  const float* wk = (const float*)d_in[3];
  const float* bk = (const float*)d_in[4];
  const float* wv = (const float*)d_in[5];
  const float* bv = (const float*)d_in[6];
  const float* wo = (const float*)d_in[7];
  const float* bo = (const float*)d_in[8];

  char* ws = (char*)d_ws;
  __bf16* xb    = (__bf16*)(ws + 0);
  __bf16* wqkv  = (__bf16*)(ws + 8388608);
  __bf16* wob   = (__bf16*)(ws + 14680064);
  float*  bcat  = (float*)(ws + 16777216);
  __bf16* qkv   = (__bf16*)(ws + 16789504);
  __bf16* vt    = (__bf16*)(ws + 41955328);
  __bf16* attn  = (__bf16*)(ws + 50343936);
  float*  out   = (float*)d_out;

  pack_kernel<<<1024, 256, 0, stream>>>(
      (const float4*)x, (const float4*)wq, (const float4*)wk, (const float4*)wv,
      (const float4*)wo, (const float4*)bq, (const float4*)bk, (const float4*)bv,
      (bf16x4*)xb, (bf16x4*)wqkv, (bf16x4*)wob, (float4*)bcat);

  // fused QKV projection: M=4096, N=3072, K=1024, 256x192 phase-split kernel
  // (256 blocks = exactly 1/CU, XCD-chunked)
  gemm_qkv_256x192<<<256, 512, 0, stream>>>(xb, wqkv, bcat, qkv);

  // V transpose: vectorized bf16x8 both sides, granule-XOR LDS transpose
  vtrans_kernel<<<dim3(32, 32), 256, 0, stream>>>(qkv, vt);

  // flash attention: 1-D grid, balanced swizzle (r3 verified config)
  attn_kernel<<<1024, 256, 0, stream>>>(qkv, vt, attn);

  // output projection: M=4096, N=1024, K=1024, 128x128 phase-split kernel
  // (256 blocks = exactly 1/CU, XCD-chunked)
  gemm_out_128<<<256, 512, 0, stream>>>(attn, wob, bo, out);
}

// Round 10
// 165.292 us; speedup vs baseline: 1.1434x; 1.0381x over previous
//
#include <hip/hip_runtime.h>
#include <cstdint>

// Problem constants: B=2, L=2048, D=1024, H=16, DK=64
#define SEQ     2048
#define DMODEL  1024
#define NHEAD   16
#define DKH     64
#define NTOK    4096      // B*L
#define LDQKV   3072      // qkv buffer row stride (q|k|v)

typedef __bf16 bf16x8 __attribute__((ext_vector_type(8)));
typedef __bf16 bf16x4 __attribute__((ext_vector_type(4)));
typedef float  f32x4  __attribute__((ext_vector_type(4)));

#define MFMA_BF16(a, b, c) __builtin_amdgcn_mfma_f32_16x16x32_bf16((a), (b), (c), 0, 0, 0)

// 0.125 * log2(e): folded into wq/bq at pack time. Softmax shift dropped
// entirely — exp2(s) scales O and l identically, cancels in O/l.
#define C2F 0.18033688f

__device__ inline float fast_exp2(float x) {
#if __has_builtin(__builtin_amdgcn_exp2f)
  return __builtin_amdgcn_exp2f(x);
#else
  return __expf(x * 0.69314718056f);
#endif
}

// async global->LDS copy, 16B per lane; LDS dest is wave-uniform base + lane*16
__device__ inline void async_copy16(const void* g, void* l) {
  __builtin_amdgcn_global_load_lds(
      reinterpret_cast<const __attribute__((address_space(1))) void*>(
          reinterpret_cast<uintptr_t>(g)),
      reinterpret_cast<__attribute__((address_space(3))) void*>(
          reinterpret_cast<uintptr_t>(l)),
      16, 0, 0);
}

__device__ inline bf16x4 cvt4(float4 v) {
  bf16x4 r;
  r[0] = (__bf16)v.x; r[1] = (__bf16)v.y; r[2] = (__bf16)v.z; r[3] = (__bf16)v.w;
  return r;
}

// ---------------- pack: fp32 -> bf16 casts + weight/bias concat ----------------
__global__ __launch_bounds__(256) void pack_kernel(
    const float4* __restrict__ x,
    const float4* __restrict__ wq, const float4* __restrict__ wk,
    const float4* __restrict__ wv, const float4* __restrict__ wo,
    const float4* __restrict__ bq, const float4* __restrict__ bk,
    const float4* __restrict__ bv,
    bf16x4* __restrict__ xb, bf16x4* __restrict__ wqkv,
    bf16x4* __restrict__ wob, float4* __restrict__ bcat)
{
  const int NX = NTOK * DMODEL / 4;       // 1048576 float4 groups of x
  const int NW = DMODEL * DMODEL / 4;     // 262144 per weight
  const int TOT = NX + 4 * NW + 3 * (DMODEL / 4);
  for (int g = blockIdx.x * 256 + threadIdx.x; g < TOT; g += gridDim.x * 256) {
    if (g < NX) {
      xb[g] = cvt4(x[g]);
    } else if (g < NX + 3 * NW) {
      int g2 = g - NX;
      const float4* s = (g2 < NW) ? wq : (g2 < 2 * NW ? wk : wv);
      float4 v = s[g2 & (NW - 1)];
      if (g2 < NW) { v.x *= C2F; v.y *= C2F; v.z *= C2F; v.w *= C2F; }
      wqkv[g2] = cvt4(v);
    } else if (g < NX + 4 * NW) {
      int g3 = g - NX - 3 * NW;
      wob[g3] = cvt4(wo[g3]);
    } else {
      int g4 = g - NX - 4 * NW;
      const float4* s = (g4 < 256) ? bq : (g4 < 512 ? bk : bv);
      float4 v = s[g4 & 255];
      if (g4 < 256) { v.x *= C2F; v.y *= C2F; v.z *= C2F; v.w *= C2F; }
      bcat[g4] = v;
    }
  }
}

// ---------------- QKV GEMM, 256x192 tile, BK=64, 8 waves, phase-split ---------
// (r7 verified: 256 blocks = exactly 1/CU, XCD-chunked. Frozen.)
__global__ __launch_bounds__(512, 2) void gemm_qkv_256x192(
    const __bf16* __restrict__ A,    // xb  [4096][1024]
    const __bf16* __restrict__ W,    // wqkv [3072][1024]
    const float* __restrict__ bias,  // bcat [3072]
    __bf16* __restrict__ C)          // qkv [4096][3072]
{
  constexpr int K = 1024;
  __shared__ __bf16 sA[2][256 * 64];  // 32KB each
  __shared__ __bf16 sB[2][192 * 64];  // 24KB each
  const int tid  = threadIdx.x;
  const int wave = tid >> 6, lane = tid & 63;
  const int quad = lane >> 4, l16 = lane & 15;
  const int wm = wave >> 2, wn = wave & 3;     // 2 x 4 wave grid
  const int swl = l16 & 7;
  const int bid = blockIdx.x;
  const int xcd = bid & 7, slot = bid >> 3;
  const int mt = (xcd >> 1) * 4 + (slot >> 3);   // 0..15
  const int nt = (xcd & 1) * 8 + (slot & 7);     // 0..15
  const size_t m0 = (size_t)mt * 256;
  const size_t n0 = (size_t)nt * 192;

  // staging bases: lane -> (row = chunk*8 + lane>>3, LDS granule lane&7,
  // source granule pre-swizzled by row&7)
  const int srow = lane >> 3;
  const int sgr  = (lane & 7) ^ srow;
  const __bf16* pA = A + (m0 + srow) * K + sgr * 8;
  const __bf16* pB = W + (n0 + srow) * K + sgr * 8;

  f32x4 acc[8][3];
  const f32x4 z = {0.f, 0.f, 0.f, 0.f};
#pragma unroll
  for (int i = 0; i < 8; ++i)
#pragma unroll
    for (int j = 0; j < 3; ++j) acc[i][j] = z;

#define STAGE_QKV(buf, k0)                                                    \
  {                                                                           \
    _Pragma("unroll")                                                         \
    for (int L = 0; L < 4; ++L) {          /* A: 32 chunks of 8 rows */       \
      const int c = L * 8 + wave;                                             \
      async_copy16(pA + (size_t)(c * 8) * K + (k0), &sA[buf][c * 512]);       \
    }                                                                         \
    _Pragma("unroll")                                                         \
    for (int L = 0; L < 3; ++L) {          /* B: 24 chunks of 8 rows */       \
      const int c = L * 8 + wave;                                             \
      async_copy16(pB + (size_t)(c * 8) * K + (k0), &sB[buf][c * 512]);       \
    }                                                                         \
  }

  int cur = 0;
  STAGE_QKV(0, 0);
  __syncthreads();                   // vmcnt(0) drain: tile 0 landed

  for (int t = 0; t < 16; ++t) {
    const __bf16* A_ = &sA[cur][0];
    const __bf16* B_ = &sB[cur][0];
    if (t + 1 < 16) STAGE_QKV(cur ^ 1, (t + 1) * 64);   // earliest issue

    bf16x8 af[4][2], bw[3][2];
    // ---- phase 1: B cols (all 3 j) + A rows 0..63 of wave; acc[0..3][*]
#pragma unroll
    for (int j = 0; j < 3; ++j) {
      const __bf16* r = B_ + (wn * 48 + j * 16 + l16) * 64;
      bw[j][0] = *(const bf16x8*)(r + ((quad ^ swl) * 8));
      bw[j][1] = *(const bf16x8*)(r + (((4 + quad) ^ swl) * 8));
    }
#pragma unroll
    for (int i = 0; i < 4; ++i) {
      const __bf16* r = A_ + (wm * 128 + i * 16 + l16) * 64;
      af[i][0] = *(const bf16x8*)(r + ((quad ^ swl) * 8));
      af[i][1] = *(const bf16x8*)(r + (((4 + quad) ^ swl) * 8));
    }
    __builtin_amdgcn_s_setprio(1);
#pragma unroll
    for (int i = 0; i < 4; ++i)
#pragma unroll
      for (int j = 0; j < 3; ++j) {
        acc[i][j] = MFMA_BF16(af[i][0], bw[j][0], acc[i][j]);
        acc[i][j] = MFMA_BF16(af[i][1], bw[j][1], acc[i][j]);
      }
    __builtin_amdgcn_s_setprio(0);
    __builtin_amdgcn_s_barrier();

    // ---- phase 2: A rows 64..127 (overwrite af); acc[4..7][*]; boundary
#pragma unroll
    for (int i = 0; i < 4; ++i) {
      const __bf16* r = A_ + (wm * 128 + 64 + i * 16 + l16) * 64;
      af[i][0] = *(const bf16x8*)(r + ((quad ^ swl) * 8));
      af[i][1] = *(const bf16x8*)(r + (((4 + quad) ^ swl) * 8));
    }
    __builtin_amdgcn_s_setprio(1);
#pragma unroll
    for (int i = 0; i < 4; ++i)
#pragma unroll
      for (int j = 0; j < 3; ++j) {
        acc[4 + i][j] = MFMA_BF16(af[i][0], bw[j][0], acc[4 + i][j]);
        acc[4 + i][j] = MFMA_BF16(af[i][1], bw[j][1], acc[4 + i][j]);
      }
    __builtin_amdgcn_s_setprio(0);
    asm volatile("s_waitcnt vmcnt(0)" ::: "memory");  // next tile landed
    __builtin_amdgcn_s_barrier();
    cur ^= 1;
  }
#undef STAGE_QKV

  float bi[3];
#pragma unroll
  for (int j = 0; j < 3; ++j) bi[j] = bias[n0 + wn * 48 + j * 16 + l16];

#pragma unroll
  for (int i = 0; i < 8; ++i)
#pragma unroll
    for (int j = 0; j < 3; ++j)
#pragma unroll
      for (int r = 0; r < 4; ++r) {
        size_t row = m0 + wm * 128 + i * 16 + quad * 4 + r;
        size_t col = n0 + wn * 48 + j * 16 + l16;
        C[row * LDQKV + col] = (__bf16)(acc[i][j][r] + bi[j]);
      }
}

// ---------------- out-proj GEMM, 128x128 tile, BK=64, 8 waves -----------------
// (r8 verified: 256 blocks = exactly 1/CU, XCD-chunked. Frozen.)
__global__ __launch_bounds__(512, 2) void gemm_out_128(
    const __bf16* __restrict__ A,    // attn [4096][1024]
    const __bf16* __restrict__ W,    // wob  [1024][1024]
    const float* __restrict__ bias,  // bo   [1024]
    float* __restrict__ C)           // out  [4096][1024]
{
  constexpr int K = 1024;
  __shared__ __bf16 sA[2][128 * 64];  // 16KB each
  __shared__ __bf16 sB[2][128 * 64];
  const int tid  = threadIdx.x;
  const int wave = tid >> 6, lane = tid & 63;
  const int quad = lane >> 4, l16 = lane & 15;
  const int wm = wave >> 2, wn = wave & 3;     // 2 x 4 wave grid
  const int swl = l16 & 7;
  const int bid = blockIdx.x;
  const int xcd = bid & 7, slot = bid >> 3;    // slot 0..31
  const int mt = xcd * 4 + (slot >> 3);        // 0..31
  const int nt = slot & 7;                     // 0..7
  const size_t m0 = (size_t)mt * 128;
  const size_t n0 = (size_t)nt * 128;

  const int srow = lane >> 3;
  const int sgr  = (lane & 7) ^ srow;
  const __bf16* pA = A + (m0 + srow) * K + sgr * 8;
  const __bf16* pB = W + (n0 + srow) * K + sgr * 8;

  f32x4 acc[4][2];
  const f32x4 z = {0.f, 0.f, 0.f, 0.f};
#pragma unroll
  for (int i = 0; i < 4; ++i)
#pragma unroll
    for (int j = 0; j < 2; ++j) acc[i][j] = z;

#define STAGE_OUT(buf, k0)                                                    \
  {                                                                           \
    _Pragma("unroll")                                                         \
    for (int L = 0; L < 2; ++L) {          /* 16 chunks of 8 rows each */     \
      const int c = L * 8 + wave;                                             \
      async_copy16(pA + (size_t)(c * 8) * K + (k0), &sA[buf][c * 512]);       \
      async_copy16(pB + (size_t)(c * 8) * K + (k0), &sB[buf][c * 512]);       \
    }                                                                         \
  }

  int cur = 0;
  STAGE_OUT(0, 0);
  __syncthreads();                   // vmcnt(0) drain: tile 0 landed

  for (int t = 0; t < 16; ++t) {
    const __bf16* A_ = &sA[cur][0];
    const __bf16* B_ = &sB[cur][0];
    if (t + 1 < 16) STAGE_OUT(cur ^ 1, (t + 1) * 64);   // earliest issue

    bf16x8 af[4][2], bw[2][2];
#pragma unroll
    for (int j = 0; j < 2; ++j) {
      const __bf16* r = B_ + (wn * 32 + j * 16 + l16) * 64;
      bw[j][0] = *(const bf16x8*)(r + ((quad ^ swl) * 8));
      bw[j][1] = *(const bf16x8*)(r + (((4 + quad) ^ swl) * 8));
    }
#pragma unroll
    for (int i = 0; i < 4; ++i) {
      const __bf16* r = A_ + (wm * 64 + i * 16 + l16) * 64;
      af[i][0] = *(const bf16x8*)(r + ((quad ^ swl) * 8));
      af[i][1] = *(const bf16x8*)(r + (((4 + quad) ^ swl) * 8));
    }
    __builtin_amdgcn_s_setprio(1);
#pragma unroll
    for (int i = 0; i < 4; ++i)
#pragma unroll
      for (int j = 0; j < 2; ++j) {
        acc[i][j] = MFMA_BF16(af[i][0], bw[j][0], acc[i][j]);
        acc[i][j] = MFMA_BF16(af[i][1], bw[j][1], acc[i][j]);
      }
    __builtin_amdgcn_s_setprio(0);
    asm volatile("s_waitcnt vmcnt(0)" ::: "memory");  // next tile landed
    __builtin_amdgcn_s_barrier();    // all reads of cur done; nxt complete
    cur ^= 1;
  }
#undef STAGE_OUT

  float bi[2];
#pragma unroll
  for (int j = 0; j < 2; ++j) bi[j] = bias[n0 + wn * 32 + j * 16 + l16];

#pragma unroll
  for (int i = 0; i < 4; ++i)
#pragma unroll
    for (int j = 0; j < 2; ++j)
#pragma unroll
      for (int r = 0; r < 4; ++r) {
        size_t row = m0 + wm * 64 + i * 16 + quad * 4 + r;
        size_t col = n0 + wn * 32 + j * 16 + l16;
        C[row * DMODEL + col] = acc[i][j][r] + bi[j];
      }
}

// ---------------- V transpose: qkv v-slice (n, d) -> vt[(b,h,dk)][l] ----------
// (r9: vectorized bf16x8 both sides, granule-XOR LDS transpose. Frozen.)
__global__ __launch_bounds__(256) void vtrans_kernel(
    const __bf16* __restrict__ qkv, __bf16* __restrict__ vt)
{
  __shared__ __bf16 t[64 * 64];        // 8KB
  const int tid = threadIdx.x;
  const int bh = blockIdx.x;           // b*16+h
  const int b = bh >> 4, h = bh & 15;
  const int l0 = blockIdx.y * 64;
  const size_t tokbase = (size_t)b * SEQ;

  // read: 512 chunks of 8 bf16; thread handles chunks tid and tid+256
#pragma unroll
  for (int p = 0; p < 2; ++p) {
    const int chunk = p * 256 + tid;
    const int row = chunk >> 3;        // token within tile
    const int gr  = chunk & 7;         // dk granule
    bf16x8 v = *(const bf16x8*)(
        qkv + (tokbase + l0 + row) * LDQKV + 2048 + h * DKH + gr * 8);
    const int g2 = gr ^ (row & 7) ^ (row >> 3);
    *(bf16x8*)(t + row * 64 + g2 * 8) = v;
  }
  __syncthreads();

  // write: 512 chunks; chunk -> (dk = chunk>>3, token group gc = chunk&7)
#pragma unroll
  for (int p = 0; p < 2; ++p) {
    const int chunk = p * 256 + tid;
    const int dk = chunk >> 3;
    const int gc = chunk & 7;
    bf16x8 o;
#pragma unroll
    for (int k = 0; k < 8; ++k) {
      const int row = gc * 8 + k;      // row&7 == k, row>>3 == gc
      const int g = (dk >> 3) ^ k ^ gc;
      o[k] = t[row * 64 + g * 8 + (dk & 7)];
    }
    *(bf16x8*)(vt + ((size_t)bh * DKH + dk) * SEQ + l0 + gc * 8) = o;
  }
}

// ---------------- MFMA flash attention (causal) -------------------------------
// r10: in-register P via K-row permutation. The old per-tile P round-trip
// through LDS (4 ds_write_b64 -> lgkmcnt -> 2 ds_read_b128) existed only to
// shuffle P across quads into A-fragment order. Instead, stage K rows
// permuted by pi: LDS row [ct1 ct0 q1 q0 r1 r0] holds key [ct1 q1 q0 ct0 r1
// r0]. Then lane (l16,quad)'s sacc[0..1] = exactly keys quad*8..+7 (ap0) and
// sacc[2..3] = keys 32+quad*8..+7 (ap1) — identity k-position mapping, V
// consumed in natural order, row-sum MFMA order-invariant, mask relabeled.
// Verified against the old pbuf XOR algebra: ap contents are BIT-IDENTICAL
// to the r3 path. Deletes pbuf (LDS 40->32KB) and the LDS chain; staging
// coalescing unchanged (row choice only picks which 128B segment each
// 8-lane group reads). Everything else frozen from r3.
__global__ __launch_bounds__(256) void attn_kernel(
    const __bf16* __restrict__ qkv,   // [4096][3072]
    const __bf16* __restrict__ vt,    // [32*64][2048]
    __bf16* __restrict__ attn)        // [4096][1024]
{
  __shared__ __bf16 sK[2][64 * 64];   // [key pi-permuted][dk], granule-swizzled
  __shared__ __bf16 sV[2][64 * 64];   // [dk][key], granule-swizzled
  const int tid  = threadIdx.x;
  const int wave = tid >> 6, lane = tid & 63;
  const int quad = lane >> 4, l16 = lane & 15;
  const int id = blockIdx.x;
  const int u = (id >> 3) & 31, v = id & 7, w = id >> 8;
  const int bh = v * 4 + w;
  const int ue = u ^ ((w >> 1) << 3);         // temporal mix across the CU's 4 blocks
  const int qb = (w & 1) ? ue : 31 - ue;
  const int b = bh >> 4, h = bh & 15;
  const int q0 = qb * 64;
  const int qw = q0 + wave * 16;              // wave's first query row
  const size_t tokbase = (size_t)b * SEQ;

  // staging: lane l -> (LDS row = l>>3, swizzled granule (l&7)^(l>>3))
  const int srow = lane >> 3;
  const int sgr  = (lane & 7) ^ srow;
  // K source row for LDS row (wave*16 + instr*8 + srow) under pi:
  //   krow = (wave>>1)*32 + (wave&1)*4 + (lane>>5)*8 + ((lane>>3)&3)
  //   instr 0 -> +0 rows, instr 1 -> +16 rows
  const int krow = (wave >> 1) * 32 + (wave & 1) * 4 + (lane >> 5) * 8 + (srow & 3);
  const __bf16* pKsrc = qkv + (tokbase + krow) * LDQKV + 1024 + h * DKH + sgr * 8;
  const __bf16* pVsrc = vt + ((size_t)bh * DKH + wave * 16 + srow) * SEQ + sgr * 8;
  const int lo = wave * 16 * 64;              // wave's slab within buffer

  bf16x8 qf[2];
#pragma unroll
  for (int s = 0; s < 2; ++s)
    qf[s] = *(const bf16x8*)(qkv + (tokbase + qw + l16) * LDQKV + h * DKH + s * 32 + quad * 8);

  bf16x8 ones;
#pragma unroll
  for (int i = 0; i < 8; ++i) ones[i] = (__bf16)1.0f;

  f32x4 o[4], lacc;
  const f32x4 z = {0.f, 0.f, 0.f, 0.f};
#pragma unroll
  for (int t = 0; t < 4; ++t) o[t] = z;
  lacc = z;

  const int swl = l16 & 7;   // K/V read-side swizzle key
  const int lim = wave * 16 + l16;   // causal limit (key-in-tile) for own queries

  // prologue: stage key-tile 0 into buffer 0
  async_copy16(pKsrc, &sK[0][lo]);
  async_copy16(pKsrc + (size_t)16 * LDQKV, &sK[0][lo + 8 * 64]);
  async_copy16(pVsrc, &sV[0][lo]);
  async_copy16(pVsrc + (size_t)8 * SEQ, &sV[0][lo + 8 * 64]);

  for (int t0 = 0; t0 <= qb; ++t0) {
    const int cur = t0 & 1, nxt = cur ^ 1;
    __syncthreads();                 // tile t0 staged; prev reads of nxt done
    if (t0 < qb) {
      const size_t koff = (size_t)(t0 + 1) * 64;
      async_copy16(pKsrc + koff * LDQKV, &sK[nxt][lo]);
      async_copy16(pKsrc + (koff + 16) * LDQKV, &sK[nxt][lo + 8 * 64]);
      async_copy16(pVsrc + koff, &sV[nxt][lo]);
      async_copy16(pVsrc + (size_t)8 * SEQ + koff, &sV[nxt][lo + 8 * 64]);
    }
    const __bf16* K_ = &sK[cur][0];
    const __bf16* V_ = &sV[cur][0];

    // S^T = K Q^T : 4 row-tiles of 16 (pi-permuted) keys; after pi, lane
    // holds keys quad*8+e (sacc[0..1]) and 32+quad*8+e (sacc[2..3]) for
    // query l16.
    f32x4 sacc[4];
    __builtin_amdgcn_s_setprio(1);
#pragma unroll
    for (int ct = 0; ct < 4; ++ct) {
      bf16x8 k0 = *(const bf16x8*)(K_ + (ct * 16 + l16) * 64 + ((quad ^ swl) * 8));
      bf16x8 k1 = *(const bf16x8*)(K_ + (ct * 16 + l16) * 64 + (((4 + quad) ^ swl) * 8));
      sacc[ct] = MFMA_BF16(k0, qf[0], z);
      sacc[ct] = MFMA_BF16(k1, qf[1], sacc[ct]);
    }
    __builtin_amdgcn_s_setprio(0);

    // P = exp2(S^T), built directly in A-fragment order (no LDS round-trip):
    // ap0 element e = key quad*8+e, ap1 element e = key 32+quad*8+e.
    bf16x8 ap0, ap1;
    if (t0 < qb) {
#pragma unroll
      for (int e = 0; e < 4; ++e) {
        ap0[e]     = (__bf16)fast_exp2(sacc[0][e]);
        ap0[4 + e] = (__bf16)fast_exp2(sacc[1][e]);
        ap1[e]     = (__bf16)fast_exp2(sacc[2][e]);
        ap1[4 + e] = (__bf16)fast_exp2(sacc[3][e]);
      }
    } else {
#pragma unroll
      for (int e = 0; e < 4; ++e) {
        const int k0i = quad * 8 + e;          // ap0 low keys
        const int k1i = quad * 8 + 4 + e;      // ap0 high keys
        ap0[e]     = (__bf16)fast_exp2(k0i      <= lim ? sacc[0][e] : -1e30f);
        ap0[4 + e] = (__bf16)fast_exp2(k1i      <= lim ? sacc[1][e] : -1e30f);
        ap1[e]     = (__bf16)fast_exp2(32 + k0i <= lim ? sacc[2][e] : -1e30f);
        ap1[4 + e] = (__bf16)fast_exp2(32 + k1i <= lim ? sacc[3][e] : -1e30f);
      }
    }

    __builtin_amdgcn_s_setprio(1);
    // l += P * 1 (row sums in C-layout: row quad*4+r = query — no shuffles)
    lacc = MFMA_BF16(ap0, ones, lacc);
    lacc = MFMA_BF16(ap1, ones, lacc);

    // O += P V : 4 dk-tiles
#pragma unroll
    for (int dt = 0; dt < 4; ++dt) {
      bf16x8 v0 = *(const bf16x8*)(V_ + (dt * 16 + l16) * 64 + ((quad ^ swl) * 8));
      bf16x8 v1 = *(const bf16x8*)(V_ + (dt * 16 + l16) * 64 + (((4 + quad) ^ swl) * 8));
      o[dt] = MFMA_BF16(ap0, v0, o[dt]);
      o[dt] = MFMA_BF16(ap1, v1, o[dt]);
    }
    __builtin_amdgcn_s_setprio(0);
  }

  float linv[4];
#pragma unroll
  for (int r = 0; r < 4; ++r) linv[r] = 1.0f / lacc[r];

#pragma unroll
  for (int dt = 0; dt < 4; ++dt)
#pragma unroll
    for (int r = 0; r < 4; ++r)
      attn[(tokbase + qw + quad * 4 + r) * DMODEL + h * DKH + dt * 16 + l16] =
          (__bf16)(o[dt][r] * linv[r]);
}

// ---------------- launch ------------------------------------------------------
extern "C" void kernel_launch(void* const* d_in, const int* in_sizes, int n_in,
                              void* d_out, int out_size, void* d_ws, size_t ws_size,
                              hipStream_t stream) {
  const float* x  = (const float*)d_in[0];
  const float* wq = (const float*)d_in[1];
  const float* bq = (const float*)d_in[2];
  const float* wk = (const float*)d_in[3];
  const float* bk = (const float*)d_in[4];
  const float* wv = (const float*)d_in[5];
  const float* bv = (const float*)d_in[6];
  const float* wo = (const float*)d_in[7];
  const float* bo = (const float*)d_in[8];

  char* ws = (char*)d_ws;
  __bf16* xb    = (__bf16*)(ws + 0);
  __bf16* wqkv  = (__bf16*)(ws + 8388608);
  __bf16* wob   = (__bf16*)(ws + 14680064);
  float*  bcat  = (float*)(ws + 16777216);
  __bf16* qkv   = (__bf16*)(ws + 16789504);
  __bf16* vt    = (__bf16*)(ws + 41955328);
  __bf16* attn  = (__bf16*)(ws + 50343936);
  float*  out   = (float*)d_out;

  pack_kernel<<<1024, 256, 0, stream>>>(
      (const float4*)x, (const float4*)wq, (const float4*)wk, (const float4*)wv,
      (const float4*)wo, (const float4*)bq, (const float4*)bk, (const float4*)bv,
      (bf16x4*)xb, (bf16x4*)wqkv, (bf16x4*)wob, (float4*)bcat);

  // fused QKV projection: M=4096, N=3072, K=1024, 256x192 phase-split kernel
  // (256 blocks = exactly 1/CU, XCD-chunked)
  gemm_qkv_256x192<<<256, 512, 0, stream>>>(xb, wqkv, bcat, qkv);

  // V transpose: vectorized bf16x8 both sides, granule-XOR LDS transpose
  vtrans_kernel<<<dim3(32, 32), 256, 0, stream>>>(qkv, vt);

  // flash attention: 1-D grid, balanced swizzle, in-register P (pi-permuted K)
  attn_kernel<<<1024, 256, 0, stream>>>(qkv, vt, attn);

  // output projection: M=4096, N=1024, K=1024, 128x128 phase-split kernel
  // (256 blocks = exactly 1/CU, XCD-chunked)
  gemm_out_128<<<256, 512, 0, stream>>>(attn, wob, bo, out);
}